// Round 11
// baseline (829.427 us; speedup 1.0000x reference)
//
#include <hip/hip_runtime.h>
#include <math.h>

typedef __attribute__((ext_vector_type(8))) short bf16x8;
typedef __attribute__((ext_vector_type(4))) float f32x4;

static __device__ __forceinline__ float fast_elu(float x) {
    return x > 0.0f ? x : __expf(x) - 1.0f;
}

static __device__ __forceinline__ unsigned short f2bf(float f) {
    unsigned int u = __float_as_uint(f);
    unsigned int r = (u + 0x7FFFu + ((u >> 16) & 1u)) >> 16;
    return (unsigned short)r;
}

static __device__ __forceinline__ bf16x8 cvt8(const float* __restrict__ s) {
    float4 a = *reinterpret_cast<const float4*>(s);
    float4 b = *reinterpret_cast<const float4*>(s + 4);
    bf16x8 r;
    r[0] = (short)f2bf(a.x); r[1] = (short)f2bf(a.y);
    r[2] = (short)f2bf(a.z); r[3] = (short)f2bf(a.w);
    r[4] = (short)f2bf(b.x); r[5] = (short)f2bf(b.y);
    r[6] = (short)f2bf(b.z); r[7] = (short)f2bf(b.w);
    return r;
}

// conv segments in 8-element units (vectorized)
#define S0 131072    // xb      [512,2048 pad from 2000]
#define S1 393216    // fcinWb  [1024,2048 pad]
#define S2 409600    // fc1Wb   [128,1024]
#define S3 410112    // Wb      [64,64]
#define S4 475648    // out1WbT [4096,128] row-permuted
#define S5 492544    // Gb      [2112,64] = tgw cols 0:64
#define CONV_BLOCKS 1924   // S5/256
#define NB 1024            // persistent grid size (4 blocks/CU x 256 CUs)

// ---------------------------------------------------------------------------
// Grid-wide barrier (manual; all NB blocks co-resident by construction).
// __threadfence() at agent scope emits L2 writeback/invalidate on gfx950,
// giving cross-XCD visibility of plain stores.
// ---------------------------------------------------------------------------
static __device__ __forceinline__ void gridbar(int* cnt, int phase) {
    __syncthreads();
    if (threadIdx.x == 0) {
        __threadfence();               // release: drain + wb L2
        atomicAdd(cnt, 1);             // device-scope by default
        const int target = phase * NB;
        while (__hip_atomic_load(cnt, __ATOMIC_RELAXED,
                                 __HIP_MEMORY_SCOPE_AGENT) < target)
            __builtin_amdgcn_s_sleep(2);
        __threadfence();               // acquire: inv L1/L2
    }
    __syncthreads();
}

// ---------------------------------------------------------------------------
// Phase device functions (verbatim from R10)
// ---------------------------------------------------------------------------
static __device__ __forceinline__ void conv_phase(
    int bx,
    const float* __restrict__ x, const float* __restrict__ fcinW,
    const float* __restrict__ fc1W, const float* __restrict__ ntW,
    const float* __restrict__ out1W, const float* __restrict__ tgw,
    unsigned short* __restrict__ xb, unsigned short* __restrict__ fcinWb,
    unsigned short* __restrict__ fc1Wb, unsigned short* __restrict__ Wb,
    unsigned short* __restrict__ out1WbT, unsigned short* __restrict__ Gb)
{
    int u = bx * 256 + threadIdx.x;
    if (u < S0) {
        int r = u >> 8, c = u & 255;
        bf16x8 v;
        if (c < 250) v = cvt8(&x[(size_t)r * 2000 + c * 8]);
        else { bf16x8 z = {0,0,0,0,0,0,0,0}; v = z; }
        *reinterpret_cast<bf16x8*>(&xb[(size_t)r * 2048 + c * 8]) = v;
    } else if (u < S1) {
        int i = u - S0;
        int r = i >> 8, c = i & 255;
        bf16x8 v;
        if (c < 250) v = cvt8(&fcinW[(size_t)r * 2000 + c * 8]);
        else { bf16x8 z = {0,0,0,0,0,0,0,0}; v = z; }
        *reinterpret_cast<bf16x8*>(&fcinWb[(size_t)r * 2048 + c * 8]) = v;
    } else if (u < S2) {
        int i8 = (u - S1) * 8;
        *reinterpret_cast<bf16x8*>(&fc1Wb[i8]) = cvt8(&fc1W[i8]);
    } else if (u < S3) {
        int i8 = (u - S2) * 8;
        *reinterpret_cast<bf16x8*>(&Wb[i8]) = cvt8(&ntW[i8]);
    } else if (u < S4) {
        int i = u - S3;
        int n = i >> 4, kc = i & 15;
        int d = n >> 6, p = n & 63;
        *reinterpret_cast<bf16x8*>(&out1WbT[(size_t)n * 128 + kc * 8]) =
            cvt8(&out1W[(size_t)((p << 6) | d) * 128 + kc * 8]);
    } else if (u < S5) {
        int i = u - S4;
        int e = i >> 3, c = i & 7;
        *reinterpret_cast<bf16x8*>(&Gb[(size_t)e * 64 + c * 8]) =
            cvt8(&tgw[(size_t)e * 2112 + c * 8]);
    }
}

static __device__ __forceinline__ void coef_phase(
    int bx, float* __restrict__ smemf,
    const float* __restrict__ coef_m, const float* __restrict__ cW,
    const float* __restrict__ cB, const float* __restrict__ attW,
    float* __restrict__ cfs)
{
    float* cf_s = smemf;            // [4][256]
    float* part = smemf + 1024;     // [4][64]
    const int t = threadIdx.x;
    const int wv = t >> 6, lane = t & 63;
    const int xy = bx * 4 + wv;
    float ls = 0.0f;
    #pragma unroll
    for (int i = 0; i < 4; ++i) {
        int idx = i * 64 + lane;
        int f = idx >> 5;
        float v = fast_elu(coef_m[xy * 8 + f] * cW[idx] + cB[idx]);
        cf_s[wv * 256 + idx] = v;
        ls += __expf(fast_elu(v));
    }
    #pragma unroll
    for (int m = 1; m < 64; m <<= 1) ls += __shfl_xor(ls, m, 64);
    __syncthreads();
    const float rs = __builtin_amdgcn_rcpf(ls);
    const int g = lane & 31, fg = lane >> 5;
    float acc = 0.0f;
    for (int f = fg * 4; f < fg * 4 + 4; ++f) {
        float lin = 0.0f;
        #pragma unroll
        for (int h = 0; h < 32; h += 4) {
            float4 Lv = *reinterpret_cast<const float4*>(&cf_s[wv * 256 + f * 32 + h]);
            float4 Wv = *reinterpret_cast<const float4*>(&attW[f * 1024 + g * 32 + h]);
            lin += Lv.x * Wv.x + Lv.y * Wv.y + Lv.z * Wv.z + Lv.w * Wv.w;
        }
        float e = __expf(fast_elu(cf_s[wv * 256 + f * 32 + g]));
        acc += fast_elu(e * lin * rs);
    }
    part[wv * 64 + lane] = acc;
    __syncthreads();
    if (lane < 32) {
        float tot = part[wv * 64 + lane] + part[wv * 64 + lane + 32];
        cfs[xy * 32 + lane] = fast_elu(tot * 0.125f);
    }
}

static __device__ __forceinline__ void att_phase(
    int o, int ic, float* __restrict__ smemf,
    const float* __restrict__ cfs, const float* __restrict__ oattW,
    float* __restrict__ att)
{
    float* L    = smemf;          // 2048
    float* red  = smemf + 2048;   // 256
    float* csum = smemf + 2304;   // 32
    const int t = threadIdx.x;
    #pragma unroll
    for (int j = 0; j < 8; ++j) L[t + 256 * j] = cfs[o * 2048 + t + 256 * j];
    __syncthreads();
    {
        int h = t & 31, ig = t >> 5;
        float ps = 0.0f;
        for (int i = ig * 8; i < ig * 8 + 8; ++i) ps += __expf(fast_elu(L[i * 32 + h]));
        red[t] = ps;
        __syncthreads();
        if (t < 32) {
            float cs = 0.0f;
            #pragma unroll
            for (int j = 0; j < 8; ++j) cs += red[j * 32 + t];
            csum[t] = cs;
        }
        __syncthreads();
    }
    int idx = ic * 256 + t;
    int i = idx >> 5, g = idx & 31;
    float lin2 = 0.0f;
    #pragma unroll
    for (int h = 0; h < 32; h += 4) {
        float4 Lv = *reinterpret_cast<const float4*>(&L[i * 32 + h]);
        float4 Wv = *reinterpret_cast<const float4*>(&oattW[i * 1024 + g * 32 + h]);
        lin2 += Lv.x * Wv.x + Lv.y * Wv.y + Lv.z * Wv.z + Lv.w * Wv.w;
    }
    float p2 = __expf(fast_elu(L[idx])) * __builtin_amdgcn_rcpf(csum[g]);
    att[o * 2048 + idx] = p2 * lin2;
}

static __device__ __forceinline__ void natt_phase(
    int bx, float* __restrict__ smemf,
    const float* __restrict__ ntW, const float* __restrict__ att,
    unsigned short* __restrict__ nattb)
{
    float* ntW_s = smemf;             // 64*65
    float* att_s = smemf + 64 * 65;   // 64*17
    const int t = threadIdx.x;
    const int d0 = bx * 16;
    #pragma unroll
    for (int j = 0; j < 16; ++j) {
        int idx = t + 256 * j;
        ntW_s[(idx >> 6) * 65 + (idx & 63)] = ntW[idx];
    }
    #pragma unroll
    for (int j = 0; j < 4; ++j) {
        int idx = t + 256 * j;
        int p = idx >> 4, dd = idx & 15;
        att_s[p * 17 + dd] = att[p * 2048 + d0 + dd];
    }
    __syncthreads();
    const int dd = t & 15, ob = (t >> 4) * 4;
    float acc[4] = {0.0f, 0.0f, 0.0f, 0.0f};
    for (int p = 0; p < 64; ++p) {
        float av = att_s[p * 17 + dd];
        #pragma unroll
        for (int i = 0; i < 4; ++i) acc[i] += ntW_s[(ob + i) * 65 + p] * av;
    }
    #pragma unroll
    for (int i = 0; i < 4; ++i)
        nattb[(ob + i) * 2048 + d0 + dd] = f2bf(acc[i]);
}

static __device__ __forceinline__ void gemm_core(
    const unsigned short* __restrict__ A, int lda,
    const unsigned short* __restrict__ B, int ldb,
    float* __restrict__ C, unsigned short* __restrict__ Cb,
    int ldc, long strideCz, const float* __restrict__ bias,
    int mode, int kchunk, int bn, int bm, int bz,
    unsigned short* __restrict__ As, unsigned short* __restrict__ Bs)
{
    const int t = threadIdx.x;
    const int w = t >> 6, lane = t & 63, l16 = lane & 15, quad = lane >> 4;
    const int n0 = bn * 64, m0 = bm * 64;
    const int kb0 = bz * kchunk;
    const int r = t >> 2, koff = (t & 3) * 8;
    if (mode == 0) C += (size_t)bz * strideCz;

    const size_t arow = (size_t)(m0 + r) * lda + koff;
    const size_t brow = (size_t)(n0 + r) * ldb + koff;
    bf16x8 av = *reinterpret_cast<const bf16x8*>(&A[arow + kb0]);
    bf16x8 bv = *reinterpret_cast<const bf16x8*>(&B[brow + kb0]);

    f32x4 acc[4] = {};
    for (int kb = kb0; kb < kb0 + kchunk; kb += 32) {
        __syncthreads();
        *reinterpret_cast<bf16x8*>(&As[r * 40 + koff]) = av;
        *reinterpret_cast<bf16x8*>(&Bs[r * 40 + koff]) = bv;
        if (kb + 32 < kb0 + kchunk) {
            av = *reinterpret_cast<const bf16x8*>(&A[arow + kb + 32]);
            bv = *reinterpret_cast<const bf16x8*>(&B[brow + kb + 32]);
        }
        __syncthreads();
        bf16x8 af = *reinterpret_cast<const bf16x8*>(&As[(w * 16 + l16) * 40 + quad * 8]);
        #pragma unroll
        for (int nt = 0; nt < 4; ++nt) {
            bf16x8 bf = *reinterpret_cast<const bf16x8*>(&Bs[(nt * 16 + l16) * 40 + quad * 8]);
            acc[nt] = __builtin_amdgcn_mfma_f32_16x16x32_bf16(af, bf, acc[nt], 0, 0, 0);
        }
    }
    #pragma unroll
    for (int nt = 0; nt < 4; ++nt)
        #pragma unroll
        for (int i = 0; i < 4; ++i) {
            int m = m0 + w * 16 + quad * 4 + i;
            int n = n0 + nt * 16 + l16;
            if (mode == 0) {
                C[(size_t)m * ldc + n] = acc[nt][i];
            } else {
                int bidx = (((n & 63) << 6) | (n >> 6));
                float v = acc[nt][i] + bias[bidx];
                v = fmaxf(v, 0.0f);
                Cb[(size_t)m * ldc + n] = f2bf(v);
            }
        }
}

static __device__ __forceinline__ void gemm_tgwa_core(
    const float* __restrict__ tgw,
    const unsigned short* __restrict__ B,   // nattb [64,2048]
    float* __restrict__ C, long strideCz,
    int kchunk, int bm, int bz,
    unsigned short* __restrict__ As, unsigned short* __restrict__ Bs)
{
    const int t = threadIdx.x;
    const int w = t >> 6, lane = t & 63, l16 = lane & 15, quad = lane >> 4;
    const int m0 = bm * 64;
    const int kb0 = bz * kchunk;
    const int r = t >> 2, koff = (t & 3) * 8;
    C += (size_t)bz * strideCz;

    const float* arow = tgw + (size_t)(m0 + r) * 2112 + 64 + koff;
    const unsigned short* brow = B + (size_t)r * 2048 + koff;
    bf16x8 av = cvt8(arow + kb0);
    bf16x8 bv = *reinterpret_cast<const bf16x8*>(brow + kb0);

    f32x4 acc[4] = {};
    for (int kb = kb0; kb < kb0 + kchunk; kb += 32) {
        __syncthreads();
        *reinterpret_cast<bf16x8*>(&As[r * 40 + koff]) = av;
        *reinterpret_cast<bf16x8*>(&Bs[r * 40 + koff]) = bv;
        if (kb + 32 < kb0 + kchunk) {
            av = cvt8(arow + kb + 32);
            bv = *reinterpret_cast<const bf16x8*>(brow + kb + 32);
        }
        __syncthreads();
        bf16x8 af = *reinterpret_cast<const bf16x8*>(&As[(w * 16 + l16) * 40 + quad * 8]);
        #pragma unroll
        for (int nt = 0; nt < 4; ++nt) {
            bf16x8 bf = *reinterpret_cast<const bf16x8*>(&Bs[(nt * 16 + l16) * 40 + quad * 8]);
            acc[nt] = __builtin_amdgcn_mfma_f32_16x16x32_bf16(af, bf, acc[nt], 0, 0, 0);
        }
    }
    #pragma unroll
    for (int nt = 0; nt < 4; ++nt)
        #pragma unroll
        for (int i = 0; i < 4; ++i) {
            int m = m0 + w * 16 + quad * 4 + i;
            int n = nt * 16 + l16;
            C[(size_t)m * 64 + n] = acc[nt][i];
        }
}

static __device__ __forceinline__ void gemm_fa_core(
    const float* __restrict__ Ap, int lda, long apstride, int nparts,
    const float* __restrict__ abias,
    const unsigned short* __restrict__ B, int ldb,
    float* __restrict__ C, unsigned short* __restrict__ Cb,
    int ldc, long strideCz, const float* __restrict__ bias,
    int mode, int kchunk, int bn, int bm, int bz,
    unsigned short* __restrict__ As, unsigned short* __restrict__ Bs)
{
    const int t = threadIdx.x;
    const int w = t >> 6, lane = t & 63, l16 = lane & 15, quad = lane >> 4;
    const int n0 = bn * 64, m0 = bm * 64;
    const int kb0 = bz * kchunk;
    const int r = t >> 2, koff = (t & 3) * 8;
    if (mode == 0) C += (size_t)bz * strideCz;

    f32x4 acc[4] = {};
    for (int kb = kb0; kb < kb0 + kchunk; kb += 32) {
        float a8[8];
        {
            const float* base = &Ap[(size_t)(m0 + r) * lda + kb + koff];
            float4 s0 = *reinterpret_cast<const float4*>(base);
            float4 s1 = *reinterpret_cast<const float4*>(base + 4);
            for (int j = 1; j < nparts; ++j) {
                const float* pj = base + (size_t)j * apstride;
                float4 p0 = *reinterpret_cast<const float4*>(pj);
                float4 p1 = *reinterpret_cast<const float4*>(pj + 4);
                s0.x += p0.x; s0.y += p0.y; s0.z += p0.z; s0.w += p0.w;
                s1.x += p1.x; s1.y += p1.y; s1.z += p1.z; s1.w += p1.w;
            }
            float4 b0 = *reinterpret_cast<const float4*>(&abias[kb + koff]);
            float4 b1 = *reinterpret_cast<const float4*>(&abias[kb + koff + 4]);
            a8[0] = fmaxf(s0.x + b0.x, 0.0f); a8[1] = fmaxf(s0.y + b0.y, 0.0f);
            a8[2] = fmaxf(s0.z + b0.z, 0.0f); a8[3] = fmaxf(s0.w + b0.w, 0.0f);
            a8[4] = fmaxf(s1.x + b1.x, 0.0f); a8[5] = fmaxf(s1.y + b1.y, 0.0f);
            a8[6] = fmaxf(s1.z + b1.z, 0.0f); a8[7] = fmaxf(s1.w + b1.w, 0.0f);
        }
        bf16x8 bv = *reinterpret_cast<const bf16x8*>(&B[(size_t)(n0 + r) * ldb + kb + koff]);
        __syncthreads();
        ushort4 lo, hi;
        lo.x = f2bf(a8[0]); lo.y = f2bf(a8[1]); lo.z = f2bf(a8[2]); lo.w = f2bf(a8[3]);
        hi.x = f2bf(a8[4]); hi.y = f2bf(a8[5]); hi.z = f2bf(a8[6]); hi.w = f2bf(a8[7]);
        *reinterpret_cast<ushort4*>(&As[r * 40 + koff]) = lo;
        *reinterpret_cast<ushort4*>(&As[r * 40 + koff + 4]) = hi;
        *reinterpret_cast<bf16x8*>(&Bs[r * 40 + koff]) = bv;
        __syncthreads();
        bf16x8 af = *reinterpret_cast<const bf16x8*>(&As[(w * 16 + l16) * 40 + quad * 8]);
        #pragma unroll
        for (int nt = 0; nt < 4; ++nt) {
            bf16x8 bf = *reinterpret_cast<const bf16x8*>(&Bs[(nt * 16 + l16) * 40 + quad * 8]);
            acc[nt] = __builtin_amdgcn_mfma_f32_16x16x32_bf16(af, bf, acc[nt], 0, 0, 0);
        }
    }
    #pragma unroll
    for (int nt = 0; nt < 4; ++nt)
        #pragma unroll
        for (int i = 0; i < 4; ++i) {
            int m = m0 + w * 16 + quad * 4 + i;
            int n = n0 + nt * 16 + l16;
            if (mode == 0) {
                C[(size_t)m * ldc + n] = acc[nt][i];
            } else {
                int bidx = (((n & 63) << 6) | (n >> 6));
                float v = acc[nt][i] + bias[bidx];
                v = fmaxf(v, 0.0f);
                Cb[(size_t)m * ldc + n] = f2bf(v);
            }
        }
}

static __device__ __forceinline__ void nt1f_phase(
    int b, unsigned short* __restrict__ smemu,
    const unsigned short* __restrict__ hbT, const unsigned short* __restrict__ Wb,
    unsigned short* __restrict__ nt1b)
{
    unsigned short* HtT   = smemu;             // [64][72]
    unsigned short* nt1_s = smemu + 64 * 72;   // [64][72]
    const int t = threadIdx.x;
    const int w = t >> 6, lane = t & 63, l16 = lane & 15, quad = lane >> 4;

    const unsigned short* src = hbT + (size_t)b * 4096;
    #pragma unroll
    for (int j = 0; j < 2; ++j) {
        int c = t + j * 256;
        *reinterpret_cast<bf16x8*>(&HtT[(c >> 3) * 72 + (c & 7) * 8]) =
            *reinterpret_cast<const bf16x8*>(&src[c * 8]);
    }
    __syncthreads();

    bf16x8 aW[2];
    #pragma unroll
    for (int h = 0; h < 2; ++h)
        aW[h] = *reinterpret_cast<const bf16x8*>(&Wb[(w * 16 + l16) * 64 + h * 32 + quad * 8]);
    #pragma unroll
    for (int dt = 0; dt < 4; ++dt) {
        f32x4 acc = {0.0f, 0.0f, 0.0f, 0.0f};
        #pragma unroll
        for (int h = 0; h < 2; ++h) {
            bf16x8 bf = *reinterpret_cast<const bf16x8*>(
                &HtT[(dt * 16 + l16) * 72 + h * 32 + quad * 8]);
            acc = __builtin_amdgcn_mfma_f32_16x16x32_bf16(aW[h], bf, acc, 0, 0, 0);
        }
        #pragma unroll
        for (int i = 0; i < 4; ++i)
            nt1_s[(w * 16 + quad * 4 + i) * 72 + dt * 16 + l16] = f2bf(acc[i]);
    }
    __syncthreads();
    #pragma unroll
    for (int j = 0; j < 2; ++j) {
        int c = t + j * 256;
        *reinterpret_cast<bf16x8*>(&nt1b[(size_t)b * 4096 + c * 8]) =
            *reinterpret_cast<const bf16x8*>(&nt1_s[(c >> 3) * 72 + (c & 7) * 8]);
    }
    __syncthreads();   // protect smem reuse across grid-stride callers
}

static __device__ __forceinline__ void final_phase(
    int eb, int b0, unsigned short* __restrict__ nls, float* __restrict__ zsf,
    const unsigned short* __restrict__ nt1b, const unsigned short* __restrict__ Gb,
    const float* __restrict__ cmatT, const float* __restrict__ outW,
    float* __restrict__ zpart)
{
    const int t = threadIdx.x;
    const int w = t >> 6, lane = t & 63, l16 = lane & 15, quad = lane >> 4;
    const int ew = eb * 64 + w * 16;

    bf16x8 ga[2];
    #pragma unroll
    for (int h = 0; h < 2; ++h)
        ga[h] = *reinterpret_cast<const bf16x8*>(
            &Gb[(size_t)(ew + l16) * 64 + h * 32 + quad * 8]);
    float cm[4][4];
    #pragma unroll
    for (int nt = 0; nt < 4; ++nt)
        #pragma unroll
        for (int i = 0; i < 4; ++i)
            cm[nt][i] = cmatT[(size_t)(ew + quad * 4 + i) * 64 + nt * 16 + l16];
    float wv[4];
    #pragma unroll
    for (int i = 0; i < 4; ++i) wv[i] = outW[ew + quad * 4 + i];

    const int c0 = t, c1 = t + 256;
    bf16x8 v0 = *reinterpret_cast<const bf16x8*>(&nt1b[(size_t)b0 * 4096 + c0 * 8]);
    bf16x8 v1 = *reinterpret_cast<const bf16x8*>(&nt1b[(size_t)b0 * 4096 + c1 * 8]);
    *reinterpret_cast<bf16x8*>(&nls[(c0 >> 3) * 72 + (c0 & 7) * 8]) = v0;
    *reinterpret_cast<bf16x8*>(&nls[(c1 >> 3) * 72 + (c1 & 7) * 8]) = v1;
    __syncthreads();

    int cur = 0;
    for (int bi = 0; bi < 16; ++bi) {
        if (bi < 15) {
            v0 = *reinterpret_cast<const bf16x8*>(
                &nt1b[(size_t)(b0 + bi + 1) * 4096 + c0 * 8]);
            v1 = *reinterpret_cast<const bf16x8*>(
                &nt1b[(size_t)(b0 + bi + 1) * 4096 + c1 * 8]);
        }
        if (bi > 0 && t < 64) {
            const float* z = zsf + ((bi - 1) & 1) * 256;
            zpart[((size_t)eb * 512 + b0 + bi - 1) * 64 + t] =
                z[t] + z[64 + t] + z[128 + t] + z[192 + t];
        }
        float zo[4] = {0.0f, 0.0f, 0.0f, 0.0f};
        #pragma unroll
        for (int nt = 0; nt < 4; ++nt) {
            bf16x8 bf0 = *reinterpret_cast<const bf16x8*>(
                &nls[cur * 4608 + (nt * 16 + l16) * 72 + quad * 8]);
            bf16x8 bf1 = *reinterpret_cast<const bf16x8*>(
                &nls[cur * 4608 + (nt * 16 + l16) * 72 + 32 + quad * 8]);
            f32x4 acc = {cm[nt][0], cm[nt][1], cm[nt][2], cm[nt][3]};
            acc = __builtin_amdgcn_mfma_f32_16x16x32_bf16(ga[0], bf0, acc, 0, 0, 0);
            acc = __builtin_amdgcn_mfma_f32_16x16x32_bf16(ga[1], bf1, acc, 0, 0, 0);
            #pragma unroll
            for (int i = 0; i < 4; ++i)
                zo[nt] += __builtin_amdgcn_rcpf(1.0f + __expf(-acc[i])) * wv[i];
        }
        #pragma unroll
        for (int nt = 0; nt < 4; ++nt) {
            zo[nt] += __shfl_xor(zo[nt], 16, 64);
            zo[nt] += __shfl_xor(zo[nt], 32, 64);
        }
        if (quad == 0) {
            #pragma unroll
            for (int nt = 0; nt < 4; ++nt)
                zsf[(bi & 1) * 256 + w * 64 + nt * 16 + l16] = zo[nt];
        }
        if (bi < 15) {
            *reinterpret_cast<bf16x8*>(&nls[(1 - cur) * 4608 + (c0 >> 3) * 72 + (c0 & 7) * 8]) = v0;
            *reinterpret_cast<bf16x8*>(&nls[(1 - cur) * 4608 + (c1 >> 3) * 72 + (c1 & 7) * 8]) = v1;
        }
        __syncthreads();
        cur ^= 1;
    }
    if (t < 64) {   // tail: b0+15 (15&1 = 1)
        const float* z = zsf + 256;
        zpart[((size_t)eb * 512 + b0 + 15) * 64 + t] =
            z[t] + z[64 + t] + z[128 + t] + z[192 + t];
    }
    __syncthreads();   // protect smem reuse across grid-stride callers
}

// ---------------------------------------------------------------------------
// The single persistent mega kernel: 7 phases, 6 grid barriers.
// ---------------------------------------------------------------------------
__global__ __launch_bounds__(256, 4) void mega(
    const float* x, const float* fcinW, const float* fc_in_b,
    const float* fc1W, const float* fc1_b, const float* out1W, const float* out1_b,
    const float* cW, const float* cB, const float* cattW, const float* oattW,
    const float* ntW, const float* tgw, const float* outW, const float* outB,
    const float* preluA, const float* coef_m, float* out,
    unsigned short* xb, unsigned short* fcinWb, float* cpT, float* h1p,
    unsigned short* nt1b, float* zpart, unsigned short* fc1Wb, float* h2p,
    unsigned short* out1WbT, unsigned short* hbT, unsigned short* Wb,
    unsigned short* Gb, float* att, unsigned short* nattb, float* cmatT,
    float* cfs, int* cnt)
{
    __shared__ __align__(16) unsigned char smem[21504];
    float* smemf = (float*)smem;
    unsigned short* smemu = (unsigned short*)smem;
    const int bx = blockIdx.x;

    // P0: conversions (grid-stride) + coef (all blocks)
    for (int u = bx; u < CONV_BLOCKS; u += NB)
        conv_phase(u, x, fcinW, fc1W, ntW, out1W, tgw,
                   xb, fcinWb, fc1Wb, Wb, out1WbT, Gb);
    coef_phase(bx, smemf, coef_m, cW, cB, cattW, cfs);
    gridbar(cnt, 1);

    // P1: fc_in GEMM (512) + att (512)
    if (bx < 512)
        gemm_core(xb, 2048, fcinWb, 2048, h1p, nullptr, 1024, 524288L,
                  nullptr, 0, 512, bx & 15, (bx >> 4) & 7, bx >> 7,
                  smemu, smemu + 2560);
    else
        att_phase((bx - 512) & 63, (bx - 512) >> 6, smemf, cfs, oattW, att);
    gridbar(cnt, 2);

    // P2: fc1 GEMM(fa) (64) + natt (128)
    if (bx < 64)
        gemm_fa_core(h1p, 1024, 524288L, 4, fc_in_b, fc1Wb, 1024,
                     h2p, nullptr, 128, 65536L, nullptr, 0, 256,
                     bx & 1, (bx >> 1) & 7, bx >> 4, smemu, smemu + 2560);
    else if (bx < 192)
        natt_phase(bx - 64, smemf, ntW, att, nattb);
    gridbar(cnt, 3);

    // P3: out1 GEMM(fa) (512) + cmat GEMM (264)
    if (bx < 512)
        gemm_fa_core(h2p, 128, 65536L, 4, fc1_b, out1WbT, 128,
                     nullptr, hbT, 4096, 0L, out1_b, 2, 128,
                     bx & 63, bx >> 6, 0, smemu, smemu + 2560);
    else if (bx < 776) {
        int b2 = bx - 512;
        gemm_tgwa_core(tgw, nattb, cpT, 135168L, 256,
                       b2 % 33, b2 / 33, smemu, smemu + 2560);
    }
    gridbar(cnt, 4);

    // P4: nt1f (512) + cmat reduce (528, grid-stride over upper half)
    if (bx < 512) {
        nt1f_phase(bx, smemu, hbT, Wb, nt1b);
    } else {
        for (int u = bx - 512; u < 528; u += 512) {
            int i = u * 256 + threadIdx.x;
            float a = 0.0f;
            #pragma unroll
            for (int j = 0; j < 8; ++j) a += cpT[i + (long)j * 135168L];
            cmatT[i] = a;
        }
    }
    gridbar(cnt, 5);

    // P5: final (1056 units, grid-stride)
    for (int u = bx; u < 1056; u += NB)
        final_phase(u >> 5, (u & 31) * 16, smemu, (float*)(smem + 18432),
                    nt1b, Gb, cmatT, outW, zpart);
    gridbar(cnt, 6);

    // P6: finish (128 units)
    if (bx < 128) {
        int i = bx * 256 + threadIdx.x;
        float z = 0.0f;
        for (int j = 0; j < 33; ++j) z += zpart[(size_t)j * 32768 + i];
        z += outB[0];
        float pa = preluA[0];
        out[i] = (z >= 0.0f) ? z : pa * z;
    }
}

extern "C" void kernel_launch(void* const* d_in, const int* in_sizes, int n_in,
                              void* d_out, int out_size, void* d_ws, size_t ws_size,
                              hipStream_t stream)
{
    const float* x       = (const float*)d_in[0];
    const float* fc_in_W = (const float*)d_in[1];
    const float* fc_in_b = (const float*)d_in[2];
    const float* fc1_W   = (const float*)d_in[3];
    const float* fc1_b   = (const float*)d_in[4];
    const float* out1_W  = (const float*)d_in[5];
    const float* out1_b  = (const float*)d_in[6];
    const float* cW      = (const float*)d_in[7];
    const float* cB      = (const float*)d_in[8];
    const float* cattW   = (const float*)d_in[9];
    const float* oattW   = (const float*)d_in[10];
    const float* ntW     = (const float*)d_in[11];
    const float* tgw     = (const float*)d_in[12];
    const float* outW    = (const float*)d_in[13];
    const float* outB    = (const float*)d_in[14];
    const float* preluA  = (const float*)d_in[15];
    const float* coef_m  = (const float*)d_in[16];
    float* out = (float*)d_out;
    float* ws  = (float*)d_ws;

    // workspace layout (float offsets); aliased regions are phase-ordered
    unsigned short* xb      = (unsigned short*)(ws + 0);          // P0w, P1r
    unsigned short* fcinWb  = (unsigned short*)(ws + 524288);     // P0w, P1r
    float*          cpT     = ws + 0;                             // P3w, P4r (xb/fcinWb dead)
    float*          h1p     = ws + 1572864;                       // P1w, P2r
    unsigned short* nt1b    = (unsigned short*)(ws + 1572864);    // P4w, P5r (h1p dead)
    float*          zpart   = ws + 2621440;                       // P5w, P6r (h1p tail+fc1Wb dead)
    unsigned short* fc1Wb   = (unsigned short*)(ws + 3670016);    // P0w, P2r
    float*          h2p     = ws + 3735552;                       // P2w, P3r
    unsigned short* out1WbT = (unsigned short*)(ws + 3997696);    // P0w, P3r
    unsigned short* hbT     = (unsigned short*)(ws + 4259840);    // P3w, P4r
    unsigned short* Wb      = (unsigned short*)(ws + 5308416);    // P0w, P4r
    unsigned short* Gb      = (unsigned short*)(ws + 5310464);    // P0w, P5r
    float*          att     = ws + 7540736;                       // P1w, P2r
    unsigned short* nattb   = (unsigned short*)(ws + 7671808);    // P2w, P3r
    float*          cmatT   = ws + 7737344;                       // P4w, P5r
    float*          cfs     = ws + 7737344;                       // P0w, P1r (aliases cmatT; dead-time disjoint)
    int*            cnt     = (int*)(ws + 7872512);               // barrier counter
    // total 7,872,528 floats (~31.5 MB)

    hipMemsetAsync(cnt, 0, 64, stream);
    mega<<<NB, 256, 0, stream>>>(
        x, fc_in_W, fc_in_b, fc1_W, fc1_b, out1_W, out1_b,
        cW, cB, cattW, oattW, ntW, tgw, outW, outB, preluA, coef_m, out,
        xb, fcinWb, cpT, h1p, nt1b, zpart, fc1Wb, h2p, out1WbT, hbT,
        Wb, Gb, att, nattb, cmatT, cfs, cnt);
}

// Round 12
// 233.557 us; speedup vs baseline: 3.5513x; 3.5513x over previous
//
#include <hip/hip_runtime.h>
#include <math.h>

typedef __attribute__((ext_vector_type(8))) short bf16x8;
typedef __attribute__((ext_vector_type(4))) float f32x4;

static __device__ __forceinline__ float fast_elu(float x) {
    return x > 0.0f ? x : __expf(x) - 1.0f;
}

static __device__ __forceinline__ unsigned short f2bf(float f) {
    unsigned int u = __float_as_uint(f);
    unsigned int r = (u + 0x7FFFu + ((u >> 16) & 1u)) >> 16;
    return (unsigned short)r;
}

static __device__ __forceinline__ bf16x8 cvt8(const float* __restrict__ s) {
    float4 a = *reinterpret_cast<const float4*>(s);
    float4 b = *reinterpret_cast<const float4*>(s + 4);
    bf16x8 r;
    r[0] = (short)f2bf(a.x); r[1] = (short)f2bf(a.y);
    r[2] = (short)f2bf(a.z); r[3] = (short)f2bf(a.w);
    r[4] = (short)f2bf(b.x); r[5] = (short)f2bf(b.y);
    r[6] = (short)f2bf(b.z); r[7] = (short)f2bf(b.w);
    return r;
}

// conv segments in 8-element units (vectorized)
#define S0 131072    // xb      [512,2048 pad from 2000]
#define S1 393216    // fcinWb  [1024,2048 pad]
#define S2 409600    // fc1Wb   [128,1024]
#define S3 410112    // Wb      [64,64]
#define S4 475648    // out1WbT [4096,128] row-permuted
#define S5 492544    // Gb      [2112,64] = tgw cols 0:64
#define CONV_BLOCKS 1924   // S5/256

// ---------------------------------------------------------------------------
// Phase device functions (verbatim from R10)
// ---------------------------------------------------------------------------
static __device__ __forceinline__ void conv_phase(
    int bx,
    const float* __restrict__ x, const float* __restrict__ fcinW,
    const float* __restrict__ fc1W, const float* __restrict__ ntW,
    const float* __restrict__ out1W, const float* __restrict__ tgw,
    unsigned short* __restrict__ xb, unsigned short* __restrict__ fcinWb,
    unsigned short* __restrict__ fc1Wb, unsigned short* __restrict__ Wb,
    unsigned short* __restrict__ out1WbT, unsigned short* __restrict__ Gb)
{
    int u = bx * 256 + threadIdx.x;
    if (u < S0) {
        int r = u >> 8, c = u & 255;
        bf16x8 v;
        if (c < 250) v = cvt8(&x[(size_t)r * 2000 + c * 8]);
        else { bf16x8 z = {0,0,0,0,0,0,0,0}; v = z; }
        *reinterpret_cast<bf16x8*>(&xb[(size_t)r * 2048 + c * 8]) = v;
    } else if (u < S1) {
        int i = u - S0;
        int r = i >> 8, c = i & 255;
        bf16x8 v;
        if (c < 250) v = cvt8(&fcinW[(size_t)r * 2000 + c * 8]);
        else { bf16x8 z = {0,0,0,0,0,0,0,0}; v = z; }
        *reinterpret_cast<bf16x8*>(&fcinWb[(size_t)r * 2048 + c * 8]) = v;
    } else if (u < S2) {
        int i8 = (u - S1) * 8;
        *reinterpret_cast<bf16x8*>(&fc1Wb[i8]) = cvt8(&fc1W[i8]);
    } else if (u < S3) {
        int i8 = (u - S2) * 8;
        *reinterpret_cast<bf16x8*>(&Wb[i8]) = cvt8(&ntW[i8]);
    } else if (u < S4) {
        int i = u - S3;
        int n = i >> 4, kc = i & 15;
        int d = n >> 6, p = n & 63;
        *reinterpret_cast<bf16x8*>(&out1WbT[(size_t)n * 128 + kc * 8]) =
            cvt8(&out1W[(size_t)((p << 6) | d) * 128 + kc * 8]);
    } else if (u < S5) {
        int i = u - S4;
        int e = i >> 3, c = i & 7;
        *reinterpret_cast<bf16x8*>(&Gb[(size_t)e * 64 + c * 8]) =
            cvt8(&tgw[(size_t)e * 2112 + c * 8]);
    }
}

static __device__ __forceinline__ void coef_phase(
    int bx, float* __restrict__ smemf,
    const float* __restrict__ coef_m, const float* __restrict__ cW,
    const float* __restrict__ cB, const float* __restrict__ attW,
    float* __restrict__ cfs)
{
    float* cf_s = smemf;            // [4][256]
    float* part = smemf + 1024;     // [4][64]
    const int t = threadIdx.x;
    const int wv = t >> 6, lane = t & 63;
    const int xy = bx * 4 + wv;
    float ls = 0.0f;
    #pragma unroll
    for (int i = 0; i < 4; ++i) {
        int idx = i * 64 + lane;
        int f = idx >> 5;
        float v = fast_elu(coef_m[xy * 8 + f] * cW[idx] + cB[idx]);
        cf_s[wv * 256 + idx] = v;
        ls += __expf(fast_elu(v));
    }
    #pragma unroll
    for (int m = 1; m < 64; m <<= 1) ls += __shfl_xor(ls, m, 64);
    __syncthreads();
    const float rs = __builtin_amdgcn_rcpf(ls);
    const int g = lane & 31, fg = lane >> 5;
    float acc = 0.0f;
    for (int f = fg * 4; f < fg * 4 + 4; ++f) {
        float lin = 0.0f;
        #pragma unroll
        for (int h = 0; h < 32; h += 4) {
            float4 Lv = *reinterpret_cast<const float4*>(&cf_s[wv * 256 + f * 32 + h]);
            float4 Wv = *reinterpret_cast<const float4*>(&attW[f * 1024 + g * 32 + h]);
            lin += Lv.x * Wv.x + Lv.y * Wv.y + Lv.z * Wv.z + Lv.w * Wv.w;
        }
        float e = __expf(fast_elu(cf_s[wv * 256 + f * 32 + g]));
        acc += fast_elu(e * lin * rs);
    }
    part[wv * 64 + lane] = acc;
    __syncthreads();
    if (lane < 32) {
        float tot = part[wv * 64 + lane] + part[wv * 64 + lane + 32];
        cfs[xy * 32 + lane] = fast_elu(tot * 0.125f);
    }
}

static __device__ __forceinline__ void att_phase(
    int o, int ic, float* __restrict__ smemf,
    const float* __restrict__ cfs, const float* __restrict__ oattW,
    float* __restrict__ att)
{
    float* L    = smemf;          // 2048
    float* red  = smemf + 2048;   // 256
    float* csum = smemf + 2304;   // 32
    const int t = threadIdx.x;
    #pragma unroll
    for (int j = 0; j < 8; ++j) L[t + 256 * j] = cfs[o * 2048 + t + 256 * j];
    __syncthreads();
    {
        int h = t & 31, ig = t >> 5;
        float ps = 0.0f;
        for (int i = ig * 8; i < ig * 8 + 8; ++i) ps += __expf(fast_elu(L[i * 32 + h]));
        red[t] = ps;
        __syncthreads();
        if (t < 32) {
            float cs = 0.0f;
            #pragma unroll
            for (int j = 0; j < 8; ++j) cs += red[j * 32 + t];
            csum[t] = cs;
        }
        __syncthreads();
    }
    int idx = ic * 256 + t;
    int i = idx >> 5, g = idx & 31;
    float lin2 = 0.0f;
    #pragma unroll
    for (int h = 0; h < 32; h += 4) {
        float4 Lv = *reinterpret_cast<const float4*>(&L[i * 32 + h]);
        float4 Wv = *reinterpret_cast<const float4*>(&oattW[i * 1024 + g * 32 + h]);
        lin2 += Lv.x * Wv.x + Lv.y * Wv.y + Lv.z * Wv.z + Lv.w * Wv.w;
    }
    float p2 = __expf(fast_elu(L[idx])) * __builtin_amdgcn_rcpf(csum[g]);
    att[o * 2048 + idx] = p2 * lin2;
}

static __device__ __forceinline__ void natt_phase(
    int bx, float* __restrict__ smemf,
    const float* __restrict__ ntW, const float* __restrict__ att,
    unsigned short* __restrict__ nattb)
{
    float* ntW_s = smemf;             // 64*65
    float* att_s = smemf + 64 * 65;   // 64*17
    const int t = threadIdx.x;
    const int d0 = bx * 16;
    #pragma unroll
    for (int j = 0; j < 16; ++j) {
        int idx = t + 256 * j;
        ntW_s[(idx >> 6) * 65 + (idx & 63)] = ntW[idx];
    }
    #pragma unroll
    for (int j = 0; j < 4; ++j) {
        int idx = t + 256 * j;
        int p = idx >> 4, dd = idx & 15;
        att_s[p * 17 + dd] = att[p * 2048 + d0 + dd];
    }
    __syncthreads();
    const int dd = t & 15, ob = (t >> 4) * 4;
    float acc[4] = {0.0f, 0.0f, 0.0f, 0.0f};
    for (int p = 0; p < 64; ++p) {
        float av = att_s[p * 17 + dd];
        #pragma unroll
        for (int i = 0; i < 4; ++i) acc[i] += ntW_s[(ob + i) * 65 + p] * av;
    }
    #pragma unroll
    for (int i = 0; i < 4; ++i)
        nattb[(ob + i) * 2048 + d0 + dd] = f2bf(acc[i]);
}

static __device__ __forceinline__ void gemm_core(
    const unsigned short* __restrict__ A, int lda,
    const unsigned short* __restrict__ B, int ldb,
    float* __restrict__ C, unsigned short* __restrict__ Cb,
    int ldc, long strideCz, const float* __restrict__ bias,
    int mode, int kchunk, int bn, int bm, int bz,
    unsigned short* __restrict__ As, unsigned short* __restrict__ Bs)
{
    const int t = threadIdx.x;
    const int w = t >> 6, lane = t & 63, l16 = lane & 15, quad = lane >> 4;
    const int n0 = bn * 64, m0 = bm * 64;
    const int kb0 = bz * kchunk;
    const int r = t >> 2, koff = (t & 3) * 8;
    if (mode == 0) C += (size_t)bz * strideCz;

    const size_t arow = (size_t)(m0 + r) * lda + koff;
    const size_t brow = (size_t)(n0 + r) * ldb + koff;
    bf16x8 av = *reinterpret_cast<const bf16x8*>(&A[arow + kb0]);
    bf16x8 bv = *reinterpret_cast<const bf16x8*>(&B[brow + kb0]);

    f32x4 acc[4] = {};
    for (int kb = kb0; kb < kb0 + kchunk; kb += 32) {
        __syncthreads();
        *reinterpret_cast<bf16x8*>(&As[r * 40 + koff]) = av;
        *reinterpret_cast<bf16x8*>(&Bs[r * 40 + koff]) = bv;
        if (kb + 32 < kb0 + kchunk) {
            av = *reinterpret_cast<const bf16x8*>(&A[arow + kb + 32]);
            bv = *reinterpret_cast<const bf16x8*>(&B[brow + kb + 32]);
        }
        __syncthreads();
        bf16x8 af = *reinterpret_cast<const bf16x8*>(&As[(w * 16 + l16) * 40 + quad * 8]);
        #pragma unroll
        for (int nt = 0; nt < 4; ++nt) {
            bf16x8 bf = *reinterpret_cast<const bf16x8*>(&Bs[(nt * 16 + l16) * 40 + quad * 8]);
            acc[nt] = __builtin_amdgcn_mfma_f32_16x16x32_bf16(af, bf, acc[nt], 0, 0, 0);
        }
    }
    #pragma unroll
    for (int nt = 0; nt < 4; ++nt)
        #pragma unroll
        for (int i = 0; i < 4; ++i) {
            int m = m0 + w * 16 + quad * 4 + i;
            int n = n0 + nt * 16 + l16;
            if (mode == 0) {
                C[(size_t)m * ldc + n] = acc[nt][i];
            } else {
                int bidx = (((n & 63) << 6) | (n >> 6));
                float v = acc[nt][i] + bias[bidx];
                v = fmaxf(v, 0.0f);
                Cb[(size_t)m * ldc + n] = f2bf(v);
            }
        }
}

// cmat GEMM: A = f32 tgw (cols 64..2112) converted in staging; full K=2048.
// Writes cmatT[e,o] directly (no k-split).
static __device__ __forceinline__ void gemm_tgwa_core(
    const float* __restrict__ tgw,
    const unsigned short* __restrict__ B,   // nattb [64,2048]
    float* __restrict__ C,                  // cmatT [2112,64]
    int bm,
    unsigned short* __restrict__ As, unsigned short* __restrict__ Bs)
{
    const int t = threadIdx.x;
    const int w = t >> 6, lane = t & 63, l16 = lane & 15, quad = lane >> 4;
    const int m0 = bm * 64;
    const int r = t >> 2, koff = (t & 3) * 8;

    const float* arow = tgw + (size_t)(m0 + r) * 2112 + 64 + koff;
    const unsigned short* brow = B + (size_t)r * 2048 + koff;
    bf16x8 av = cvt8(arow);
    bf16x8 bv = *reinterpret_cast<const bf16x8*>(brow);

    f32x4 acc[4] = {};
    for (int kb = 0; kb < 2048; kb += 32) {
        __syncthreads();
        *reinterpret_cast<bf16x8*>(&As[r * 40 + koff]) = av;
        *reinterpret_cast<bf16x8*>(&Bs[r * 40 + koff]) = bv;
        if (kb + 32 < 2048) {
            av = cvt8(arow + kb + 32);
            bv = *reinterpret_cast<const bf16x8*>(brow + kb + 32);
        }
        __syncthreads();
        bf16x8 af = *reinterpret_cast<const bf16x8*>(&As[(w * 16 + l16) * 40 + quad * 8]);
        #pragma unroll
        for (int nt = 0; nt < 4; ++nt) {
            bf16x8 bf = *reinterpret_cast<const bf16x8*>(&Bs[(nt * 16 + l16) * 40 + quad * 8]);
            acc[nt] = __builtin_amdgcn_mfma_f32_16x16x32_bf16(af, bf, acc[nt], 0, 0, 0);
        }
    }
    #pragma unroll
    for (int nt = 0; nt < 4; ++nt)
        #pragma unroll
        for (int i = 0; i < 4; ++i) {
            int m = m0 + w * 16 + quad * 4 + i;
            int n = nt * 16 + l16;
            C[(size_t)m * 64 + n] = acc[nt][i];
        }
}

static __device__ __forceinline__ void gemm_fa_core(
    const float* __restrict__ Ap, int lda, long apstride, int nparts,
    const float* __restrict__ abias,
    const unsigned short* __restrict__ B, int ldb,
    float* __restrict__ C, unsigned short* __restrict__ Cb,
    int ldc, long strideCz, const float* __restrict__ bias,
    int mode, int kchunk, int bn, int bm, int bz,
    unsigned short* __restrict__ As, unsigned short* __restrict__ Bs)
{
    const int t = threadIdx.x;
    const int w = t >> 6, lane = t & 63, l16 = lane & 15, quad = lane >> 4;
    const int n0 = bn * 64, m0 = bm * 64;
    const int kb0 = bz * kchunk;
    const int r = t >> 2, koff = (t & 3) * 8;
    if (mode == 0) C += (size_t)bz * strideCz;

    f32x4 acc[4] = {};
    for (int kb = kb0; kb < kb0 + kchunk; kb += 32) {
        float a8[8];
        {
            const float* base = &Ap[(size_t)(m0 + r) * lda + kb + koff];
            float4 s0 = *reinterpret_cast<const float4*>(base);
            float4 s1 = *reinterpret_cast<const float4*>(base + 4);
            for (int j = 1; j < nparts; ++j) {
                const float* pj = base + (size_t)j * apstride;
                float4 p0 = *reinterpret_cast<const float4*>(pj);
                float4 p1 = *reinterpret_cast<const float4*>(pj + 4);
                s0.x += p0.x; s0.y += p0.y; s0.z += p0.z; s0.w += p0.w;
                s1.x += p1.x; s1.y += p1.y; s1.z += p1.z; s1.w += p1.w;
            }
            float4 b0 = *reinterpret_cast<const float4*>(&abias[kb + koff]);
            float4 b1 = *reinterpret_cast<const float4*>(&abias[kb + koff + 4]);
            a8[0] = fmaxf(s0.x + b0.x, 0.0f); a8[1] = fmaxf(s0.y + b0.y, 0.0f);
            a8[2] = fmaxf(s0.z + b0.z, 0.0f); a8[3] = fmaxf(s0.w + b0.w, 0.0f);
            a8[4] = fmaxf(s1.x + b1.x, 0.0f); a8[5] = fmaxf(s1.y + b1.y, 0.0f);
            a8[6] = fmaxf(s1.z + b1.z, 0.0f); a8[7] = fmaxf(s1.w + b1.w, 0.0f);
        }
        bf16x8 bv = *reinterpret_cast<const bf16x8*>(&B[(size_t)(n0 + r) * ldb + kb + koff]);
        __syncthreads();
        ushort4 lo, hi;
        lo.x = f2bf(a8[0]); lo.y = f2bf(a8[1]); lo.z = f2bf(a8[2]); lo.w = f2bf(a8[3]);
        hi.x = f2bf(a8[4]); hi.y = f2bf(a8[5]); hi.z = f2bf(a8[6]); hi.w = f2bf(a8[7]);
        *reinterpret_cast<ushort4*>(&As[r * 40 + koff]) = lo;
        *reinterpret_cast<ushort4*>(&As[r * 40 + koff + 4]) = hi;
        *reinterpret_cast<bf16x8*>(&Bs[r * 40 + koff]) = bv;
        __syncthreads();
        bf16x8 af = *reinterpret_cast<const bf16x8*>(&As[(w * 16 + l16) * 40 + quad * 8]);
        #pragma unroll
        for (int nt = 0; nt < 4; ++nt) {
            bf16x8 bf = *reinterpret_cast<const bf16x8*>(&Bs[(nt * 16 + l16) * 40 + quad * 8]);
            acc[nt] = __builtin_amdgcn_mfma_f32_16x16x32_bf16(af, bf, acc[nt], 0, 0, 0);
        }
    }
    #pragma unroll
    for (int nt = 0; nt < 4; ++nt)
        #pragma unroll
        for (int i = 0; i < 4; ++i) {
            int m = m0 + w * 16 + quad * 4 + i;
            int n = n0 + nt * 16 + l16;
            if (mode == 0) {
                C[(size_t)m * ldc + n] = acc[nt][i];
            } else {
                int bidx = (((n & 63) << 6) | (n >> 6));
                float v = acc[nt][i] + bias[bidx];
                v = fmaxf(v, 0.0f);
                Cb[(size_t)m * ldc + n] = f2bf(v);
            }
        }
}

// ---------------------------------------------------------------------------
// Uber kernels (launch chain: 5 launches total)
// ---------------------------------------------------------------------------
__global__ __launch_bounds__(256) void uber1(   // conv (vectorized) + coef
    const float* x, const float* fcinW, const float* fc1W, const float* ntW,
    const float* out1W, const float* tgw,
    unsigned short* xb, unsigned short* fcinWb, unsigned short* fc1Wb,
    unsigned short* Wb, unsigned short* out1WbT, unsigned short* Gb,
    const float* coef_m, const float* cW, const float* cB, const float* attW,
    float* cfs)
{
    __shared__ __align__(16) float smemf[1280];
    int bx = blockIdx.x;
    if (bx < CONV_BLOCKS)
        conv_phase(bx, x, fcinW, fc1W, ntW, out1W, tgw,
                   xb, fcinWb, fc1Wb, Wb, out1WbT, Gb);
    else
        coef_phase(bx - CONV_BLOCKS, smemf, coef_m, cW, cB, attW, cfs);
}

__global__ __launch_bounds__(256) void uber2(   // fc_in GEMM + att
    const unsigned short* xb, const unsigned short* fcinWb, float* h1p,
    const float* cfs, const float* oattW, float* att)
{
    __shared__ __align__(16) float smemf[2592];
    int bx = blockIdx.x;
    if (bx < 512) {
        unsigned short* As = (unsigned short*)smemf;
        gemm_core(xb, 2048, fcinWb, 2048, h1p, nullptr, 1024, 524288L,
                  nullptr, 0, 512, bx & 15, (bx >> 4) & 7, bx >> 7, As, As + 2560);
    } else {
        int b2 = bx - 512;
        att_phase(b2 & 63, b2 >> 6, smemf, cfs, oattW, att);
    }
}

__global__ __launch_bounds__(256) void uber3(   // fc1 GEMM(fa) + natt
    const float* h1p, const float* fc_in_b, const unsigned short* fc1Wb,
    float* h2p,
    const float* ntW, const float* att, unsigned short* nattb)
{
    __shared__ __align__(16) float smemf[5248];
    int bx = blockIdx.x;
    if (bx < 64) {
        unsigned short* As = (unsigned short*)smemf;
        gemm_fa_core(h1p, 1024, 524288L, 4, fc_in_b, fc1Wb, 1024,
                     h2p, nullptr, 128, 65536L, nullptr, 0, 256,
                     bx & 1, (bx >> 1) & 7, bx >> 4, As, As + 2560);
    } else {
        natt_phase(bx - 64, smemf, ntW, att, nattb);
    }
}

__global__ __launch_bounds__(256) void uber4(   // out1 GEMM(fa) + cmatT GEMM (full-K)
    const float* h2p, const float* fc1_b, const unsigned short* out1WbT,
    unsigned short* hbT, const float* out1_b,
    const float* tgw, const unsigned short* nattb, float* cmatT)
{
    __shared__ __align__(16) float smemf[2560];
    unsigned short* As = (unsigned short*)smemf;
    int bx = blockIdx.x;
    if (bx < 512) {
        gemm_fa_core(h2p, 128, 65536L, 4, fc1_b, out1WbT, 128,
                     nullptr, hbT, 4096, 0L, out1_b, 2, 128,
                     bx & 63, bx >> 6, 0, As, As + 2560);
    } else {
        gemm_tgwa_core(tgw, nattb, cmatT, bx - 512, As, As + 2560);
    }
}

// ---------------------------------------------------------------------------
// final2: one block per batch row b. Computes nt1 inline (MFMA via LDS),
// then software-pipelined e-loop over all 33 chunks, full z-sum in registers,
// bias + PReLU, writes out directly. Replaces nt1f + final_eblk + finish.
// ---------------------------------------------------------------------------
__global__ __launch_bounds__(256) void final2(
    const unsigned short* __restrict__ hbT,  // [512][4096] bf16, idx d*64+p
    const unsigned short* __restrict__ Wb,   // [64,64] bf16 (ntW)
    const unsigned short* __restrict__ Gb,   // [2112,64] bf16
    const float* __restrict__ cmatT,  // [2112,64]
    const float* __restrict__ outW,   // [2112]
    const float* __restrict__ outB,   // [1]
    const float* __restrict__ preluA, // [1]
    float* __restrict__ out)          // [512,64]
{
    __shared__ __align__(16) unsigned short HtT[64 * 72];   // [d][p]
    __shared__ __align__(16) unsigned short nt1_s[64 * 72]; // [o][d]
    __shared__ float zp[4][64];
    const int t = threadIdx.x;
    const int w = t >> 6, lane = t & 63, l16 = lane & 15, quad = lane >> 4;
    const int b = blockIdx.x;

    // stage hbT row b -> LDS [d][p]
    const unsigned short* src = hbT + (size_t)b * 4096;
    #pragma unroll
    for (int j = 0; j < 2; ++j) {
        int c = t + j * 256;
        *reinterpret_cast<bf16x8*>(&HtT[(c >> 3) * 72 + (c & 7) * 8]) =
            *reinterpret_cast<const bf16x8*>(&src[c * 8]);
    }
    __syncthreads();

    // nt1 = ntW x H (wave w owns o-rows [w*16,+16), all 4 d-tiles)
    bf16x8 aW[2];
    #pragma unroll
    for (int h = 0; h < 2; ++h)
        aW[h] = *reinterpret_cast<const bf16x8*>(&Wb[(w * 16 + l16) * 64 + h * 32 + quad * 8]);
    #pragma unroll
    for (int dt = 0; dt < 4; ++dt) {
        f32x4 acc = {0.0f, 0.0f, 0.0f, 0.0f};
        #pragma unroll
        for (int h = 0; h < 2; ++h) {
            bf16x8 bf = *reinterpret_cast<const bf16x8*>(
                &HtT[(dt * 16 + l16) * 72 + h * 32 + quad * 8]);
            acc = __builtin_amdgcn_mfma_f32_16x16x32_bf16(aW[h], bf, acc, 0, 0, 0);
        }
        #pragma unroll
        for (int i = 0; i < 4; ++i)
            nt1_s[(w * 16 + quad * 4 + i) * 72 + dt * 16 + l16] = f2bf(acc[i]);
    }
    __syncthreads();

    // A-fragments of nt1 for the e-loop
    bf16x8 afr[4][2];
    #pragma unroll
    for (int ot = 0; ot < 4; ++ot)
        #pragma unroll
        for (int h = 0; h < 2; ++h)
            afr[ot][h] = *reinterpret_cast<const bf16x8*>(
                &nt1_s[(ot * 16 + l16) * 72 + h * 32 + quad * 8]);

    // software-pipelined e-loop: wave w owns e-slice [ec*64 + w*16, +16)
    float zacc[4][4] = {};
    int e = w * 16 + l16;
    bf16x8 g0 = *reinterpret_cast<const bf16x8*>(&Gb[(size_t)e * 64 + quad * 8]);
    bf16x8 g1 = *reinterpret_cast<const bf16x8*>(&Gb[(size_t)e * 64 + 32 + quad * 8]);
    float wv = outW[e];
    float4 c4[4];
    #pragma unroll
    for (int ot = 0; ot < 4; ++ot)
        c4[ot] = *reinterpret_cast<const float4*>(&cmatT[(size_t)e * 64 + ot * 16 + quad * 4]);

    for (int ec = 0; ec < 33; ++ec) {
        const int en = e + 64;
        const bool more = (ec + 1 < 33);
        bf16x8 ng0, ng1; float4 nc4[4]; float nwv;
        if (more) {   // prefetch next iteration (overlaps MFMA+epilogue)
            ng0 = *reinterpret_cast<const bf16x8*>(&Gb[(size_t)en * 64 + quad * 8]);
            ng1 = *reinterpret_cast<const bf16x8*>(&Gb[(size_t)en * 64 + 32 + quad * 8]);
            nwv = outW[en];
            #pragma unroll
            for (int ot = 0; ot < 4; ++ot)
                nc4[ot] = *reinterpret_cast<const float4*>(
                    &cmatT[(size_t)en * 64 + ot * 16 + quad * 4]);
        }
        #pragma unroll
        for (int ot = 0; ot < 4; ++ot) {
            f32x4 acc = {c4[ot].x, c4[ot].y, c4[ot].z, c4[ot].w};
            acc = __builtin_amdgcn_mfma_f32_16x16x32_bf16(afr[ot][0], g0, acc, 0, 0, 0);
            acc = __builtin_amdgcn_mfma_f32_16x16x32_bf16(afr[ot][1], g1, acc, 0, 0, 0);
            #pragma unroll
            for (int i = 0; i < 4; ++i) {
                float sg = __builtin_amdgcn_rcpf(1.0f + __expf(-acc[i]));
                zacc[ot][i] += sg * wv;
            }
        }
        if (more) {
            g0 = ng0; g1 = ng1; wv = nwv;
            #pragma unroll
            for (int ot = 0; ot < 4; ++ot) c4[ot] = nc4[ot];
        }
        e = en;
    }
    // reduce over the 16 e-lanes within each quad
    #pragma unroll
    for (int m = 1; m < 16; m <<= 1)
        #pragma unroll
        for (int ot = 0; ot < 4; ++ot)
            #pragma unroll
            for (int i = 0; i < 4; ++i)
                zacc[ot][i] += __shfl_xor(zacc[ot][i], m, 64);

    if (l16 == 0) {
        #pragma unroll
        for (int ot = 0; ot < 4; ++ot)
            #pragma unroll
            for (int i = 0; i < 4; ++i)
                zp[w][ot * 16 + quad * 4 + i] = zacc[ot][i];
    }
    __syncthreads();
    if (t < 64) {
        float z = zp[0][t] + zp[1][t] + zp[2][t] + zp[3][t] + outB[0];
        float pa = preluA[0];
        out[b * 64 + t] = (z >= 0.0f) ? z : pa * z;
    }
}

extern "C" void kernel_launch(void* const* d_in, const int* in_sizes, int n_in,
                              void* d_out, int out_size, void* d_ws, size_t ws_size,
                              hipStream_t stream)
{
    const float* x       = (const float*)d_in[0];
    const float* fc_in_W = (const float*)d_in[1];
    const float* fc_in_b = (const float*)d_in[2];
    const float* fc1_W   = (const float*)d_in[3];
    const float* fc1_b   = (const float*)d_in[4];
    const float* out1_W  = (const float*)d_in[5];
    const float* out1_b  = (const float*)d_in[6];
    const float* cW      = (const float*)d_in[7];
    const float* cB      = (const float*)d_in[8];
    const float* cattW   = (const float*)d_in[9];
    const float* oattW   = (const float*)d_in[10];
    const float* ntW     = (const float*)d_in[11];
    const float* tgw     = (const float*)d_in[12];
    const float* outW    = (const float*)d_in[13];
    const float* outB    = (const float*)d_in[14];
    const float* preluA  = (const float*)d_in[15];
    const float* coef_m  = (const float*)d_in[16];
    float* out = (float*)d_out;
    float* ws  = (float*)d_ws;

    // workspace layout (float offsets); aliased regions are stream-ordered
    unsigned short* xb      = (unsigned short*)(ws + 0);          // L1w, L2r
    unsigned short* fcinWb  = (unsigned short*)(ws + 524288);     // L1w, L2r
    float*          h1p     = ws + 1572864;                       // L2w, L3r (4*524288 f)
    unsigned short* fc1Wb   = (unsigned short*)(ws + 3670016);    // L1w, L3r
    float*          h2p     = ws + 3735552;                       // L3w, L4r (4*65536 f)
    unsigned short* out1WbT = (unsigned short*)(ws + 3997696);    // L1w, L4r
    unsigned short* hbT     = (unsigned short*)(ws + 4259840);    // L4w, L5r
    unsigned short* Wb      = (unsigned short*)(ws + 5308416);    // L1w, L5r
    unsigned short* Gb      = (unsigned short*)(ws + 5310464);    // L1w, L5r
    float*          att     = ws + 7540736;                       // L2w, L3r
    unsigned short* nattb   = (unsigned short*)(ws + 7671808);    // L3w, L4r
    float*          cmatT   = ws + 7737344;                       // L4w, L5r
    float*          cfs     = ws + 7737344;                       // L1w, L2r (aliases cmatT; dead-time disjoint)
    // total 7,872,512 floats (~31.5 MB)

    // L1: conversions (vectorized) + coef
    uber1<<<CONV_BLOCKS + 1024, 256, 0, stream>>>(
        x, fc_in_W, fc1_W, ntW, out1_W, tgw,
        xb, fcinWb, fc1Wb, Wb, out1WbT, Gb,
        coef_m, cW, cB, cattW, cfs);
    // L2: fc_in GEMM + att
    uber2<<<1024, 256, 0, stream>>>(xb, fcinWb, h1p, cfs, oattW, att);
    // L3: fc1 GEMM(fa) + natt
    uber3<<<192, 256, 0, stream>>>(h1p, fc_in_b, fc1Wb, h2p, ntW, att, nattb);
    // L4: out1 GEMM(fa) + cmatT GEMM (full-K, writes cmatT directly)
    uber4<<<545, 256, 0, stream>>>(h2p, fc1_b, out1WbT, hbT, out1_b,
                                   tgw, nattb, cmatT);
    // L5: fused nt1 + final + finish
    final2<<<512, 256, 0, stream>>>(hbT, Wb, Gb, cmatT, outW, outB, preluA, out);
}

// Round 13
// 198.234 us; speedup vs baseline: 4.1841x; 1.1782x over previous
//
#include <hip/hip_runtime.h>
#include <math.h>

typedef __attribute__((ext_vector_type(8))) short bf16x8;
typedef __attribute__((ext_vector_type(4))) float f32x4;

static __device__ __forceinline__ float fast_elu(float x) {
    return x > 0.0f ? x : __expf(x) - 1.0f;
}

static __device__ __forceinline__ unsigned short f2bf(float f) {
    unsigned int u = __float_as_uint(f);
    unsigned int r = (u + 0x7FFFu + ((u >> 16) & 1u)) >> 16;
    return (unsigned short)r;
}

static __device__ __forceinline__ bf16x8 cvt8(const float* __restrict__ s) {
    float4 a = *reinterpret_cast<const float4*>(s);
    float4 b = *reinterpret_cast<const float4*>(s + 4);
    bf16x8 r;
    r[0] = (short)f2bf(a.x); r[1] = (short)f2bf(a.y);
    r[2] = (short)f2bf(a.z); r[3] = (short)f2bf(a.w);
    r[4] = (short)f2bf(b.x); r[5] = (short)f2bf(b.y);
    r[6] = (short)f2bf(b.z); r[7] = (short)f2bf(b.w);
    return r;
}

// conv segments in 8-element units (vectorized)
#define S0 131072    // xb      [512,2048 pad from 2000]
#define S1 393216    // fcinWb  [1024,2048 pad]
#define S2 409600    // fc1Wb   [128,1024]
#define S3 410112    // Wb      [64,64]
#define S4 475648    // out1WbT [4096,128] row-permuted
#define S5 492544    // Gb      [2112,64] = tgw cols 0:64
#define CONV_BLOCKS 1924   // S5/256

// ---------------------------------------------------------------------------
// Phase device functions (verbatim from R10)
// ---------------------------------------------------------------------------
static __device__ __forceinline__ void conv_phase(
    int bx,
    const float* __restrict__ x, const float* __restrict__ fcinW,
    const float* __restrict__ fc1W, const float* __restrict__ ntW,
    const float* __restrict__ out1W, const float* __restrict__ tgw,
    unsigned short* __restrict__ xb, unsigned short* __restrict__ fcinWb,
    unsigned short* __restrict__ fc1Wb, unsigned short* __restrict__ Wb,
    unsigned short* __restrict__ out1WbT, unsigned short* __restrict__ Gb)
{
    int u = bx * 256 + threadIdx.x;
    if (u < S0) {
        int r = u >> 8, c = u & 255;
        bf16x8 v;
        if (c < 250) v = cvt8(&x[(size_t)r * 2000 + c * 8]);
        else { bf16x8 z = {0,0,0,0,0,0,0,0}; v = z; }
        *reinterpret_cast<bf16x8*>(&xb[(size_t)r * 2048 + c * 8]) = v;
    } else if (u < S1) {
        int i = u - S0;
        int r = i >> 8, c = i & 255;
        bf16x8 v;
        if (c < 250) v = cvt8(&fcinW[(size_t)r * 2000 + c * 8]);
        else { bf16x8 z = {0,0,0,0,0,0,0,0}; v = z; }
        *reinterpret_cast<bf16x8*>(&fcinWb[(size_t)r * 2048 + c * 8]) = v;
    } else if (u < S2) {
        int i8 = (u - S1) * 8;
        *reinterpret_cast<bf16x8*>(&fc1Wb[i8]) = cvt8(&fc1W[i8]);
    } else if (u < S3) {
        int i8 = (u - S2) * 8;
        *reinterpret_cast<bf16x8*>(&Wb[i8]) = cvt8(&ntW[i8]);
    } else if (u < S4) {
        int i = u - S3;
        int n = i >> 4, kc = i & 15;
        int d = n >> 6, p = n & 63;
        *reinterpret_cast<bf16x8*>(&out1WbT[(size_t)n * 128 + kc * 8]) =
            cvt8(&out1W[(size_t)((p << 6) | d) * 128 + kc * 8]);
    } else if (u < S5) {
        int i = u - S4;
        int e = i >> 3, c = i & 7;
        *reinterpret_cast<bf16x8*>(&Gb[(size_t)e * 64 + c * 8]) =
            cvt8(&tgw[(size_t)e * 2112 + c * 8]);
    }
}

static __device__ __forceinline__ void coef_phase(
    int bx, float* __restrict__ smemf,
    const float* __restrict__ coef_m, const float* __restrict__ cW,
    const float* __restrict__ cB, const float* __restrict__ attW,
    float* __restrict__ cfs)
{
    float* cf_s = smemf;            // [4][256]
    float* part = smemf + 1024;     // [4][64]
    const int t = threadIdx.x;
    const int wv = t >> 6, lane = t & 63;
    const int xy = bx * 4 + wv;
    float ls = 0.0f;
    #pragma unroll
    for (int i = 0; i < 4; ++i) {
        int idx = i * 64 + lane;
        int f = idx >> 5;
        float v = fast_elu(coef_m[xy * 8 + f] * cW[idx] + cB[idx]);
        cf_s[wv * 256 + idx] = v;
        ls += __expf(fast_elu(v));
    }
    #pragma unroll
    for (int m = 1; m < 64; m <<= 1) ls += __shfl_xor(ls, m, 64);
    __syncthreads();
    const float rs = __builtin_amdgcn_rcpf(ls);
    const int g = lane & 31, fg = lane >> 5;
    float acc = 0.0f;
    for (int f = fg * 4; f < fg * 4 + 4; ++f) {
        float lin = 0.0f;
        #pragma unroll
        for (int h = 0; h < 32; h += 4) {
            float4 Lv = *reinterpret_cast<const float4*>(&cf_s[wv * 256 + f * 32 + h]);
            float4 Wv = *reinterpret_cast<const float4*>(&attW[f * 1024 + g * 32 + h]);
            lin += Lv.x * Wv.x + Lv.y * Wv.y + Lv.z * Wv.z + Lv.w * Wv.w;
        }
        float e = __expf(fast_elu(cf_s[wv * 256 + f * 32 + g]));
        acc += fast_elu(e * lin * rs);
    }
    part[wv * 64 + lane] = acc;
    __syncthreads();
    if (lane < 32) {
        float tot = part[wv * 64 + lane] + part[wv * 64 + lane + 32];
        cfs[xy * 32 + lane] = fast_elu(tot * 0.125f);
    }
}

static __device__ __forceinline__ void att_phase(
    int o, int ic, float* __restrict__ smemf,
    const float* __restrict__ cfs, const float* __restrict__ oattW,
    float* __restrict__ att)
{
    float* L    = smemf;          // 2048
    float* red  = smemf + 2048;   // 256
    float* csum = smemf + 2304;   // 32
    const int t = threadIdx.x;
    #pragma unroll
    for (int j = 0; j < 8; ++j) L[t + 256 * j] = cfs[o * 2048 + t + 256 * j];
    __syncthreads();
    {
        int h = t & 31, ig = t >> 5;
        float ps = 0.0f;
        for (int i = ig * 8; i < ig * 8 + 8; ++i) ps += __expf(fast_elu(L[i * 32 + h]));
        red[t] = ps;
        __syncthreads();
        if (t < 32) {
            float cs = 0.0f;
            #pragma unroll
            for (int j = 0; j < 8; ++j) cs += red[j * 32 + t];
            csum[t] = cs;
        }
        __syncthreads();
    }
    int idx = ic * 256 + t;
    int i = idx >> 5, g = idx & 31;
    float lin2 = 0.0f;
    #pragma unroll
    for (int h = 0; h < 32; h += 4) {
        float4 Lv = *reinterpret_cast<const float4*>(&L[i * 32 + h]);
        float4 Wv = *reinterpret_cast<const float4*>(&oattW[i * 1024 + g * 32 + h]);
        lin2 += Lv.x * Wv.x + Lv.y * Wv.y + Lv.z * Wv.z + Lv.w * Wv.w;
    }
    float p2 = __expf(fast_elu(L[idx])) * __builtin_amdgcn_rcpf(csum[g]);
    att[o * 2048 + idx] = p2 * lin2;
}

static __device__ __forceinline__ void natt_phase(
    int bx, float* __restrict__ smemf,
    const float* __restrict__ ntW, const float* __restrict__ att,
    unsigned short* __restrict__ nattb)
{
    float* ntW_s = smemf;             // 64*65
    float* att_s = smemf + 64 * 65;   // 64*17
    const int t = threadIdx.x;
    const int d0 = bx * 16;
    #pragma unroll
    for (int j = 0; j < 16; ++j) {
        int idx = t + 256 * j;
        ntW_s[(idx >> 6) * 65 + (idx & 63)] = ntW[idx];
    }
    #pragma unroll
    for (int j = 0; j < 4; ++j) {
        int idx = t + 256 * j;
        int p = idx >> 4, dd = idx & 15;
        att_s[p * 17 + dd] = att[p * 2048 + d0 + dd];
    }
    __syncthreads();
    const int dd = t & 15, ob = (t >> 4) * 4;
    float acc[4] = {0.0f, 0.0f, 0.0f, 0.0f};
    for (int p = 0; p < 64; ++p) {
        float av = att_s[p * 17 + dd];
        #pragma unroll
        for (int i = 0; i < 4; ++i) acc[i] += ntW_s[(ob + i) * 65 + p] * av;
    }
    #pragma unroll
    for (int i = 0; i < 4; ++i)
        nattb[(ob + i) * 2048 + d0 + dd] = f2bf(acc[i]);
}

static __device__ __forceinline__ void gemm_core(
    const unsigned short* __restrict__ A, int lda,
    const unsigned short* __restrict__ B, int ldb,
    float* __restrict__ C, unsigned short* __restrict__ Cb,
    int ldc, long strideCz, const float* __restrict__ bias,
    int mode, int kchunk, int bn, int bm, int bz,
    unsigned short* __restrict__ As, unsigned short* __restrict__ Bs)
{
    const int t = threadIdx.x;
    const int w = t >> 6, lane = t & 63, l16 = lane & 15, quad = lane >> 4;
    const int n0 = bn * 64, m0 = bm * 64;
    const int kb0 = bz * kchunk;
    const int r = t >> 2, koff = (t & 3) * 8;
    if (mode == 0) C += (size_t)bz * strideCz;

    const size_t arow = (size_t)(m0 + r) * lda + koff;
    const size_t brow = (size_t)(n0 + r) * ldb + koff;
    bf16x8 av = *reinterpret_cast<const bf16x8*>(&A[arow + kb0]);
    bf16x8 bv = *reinterpret_cast<const bf16x8*>(&B[brow + kb0]);

    f32x4 acc[4] = {};
    for (int kb = kb0; kb < kb0 + kchunk; kb += 32) {
        __syncthreads();
        *reinterpret_cast<bf16x8*>(&As[r * 40 + koff]) = av;
        *reinterpret_cast<bf16x8*>(&Bs[r * 40 + koff]) = bv;
        if (kb + 32 < kb0 + kchunk) {
            av = *reinterpret_cast<const bf16x8*>(&A[arow + kb + 32]);
            bv = *reinterpret_cast<const bf16x8*>(&B[brow + kb + 32]);
        }
        __syncthreads();
        bf16x8 af = *reinterpret_cast<const bf16x8*>(&As[(w * 16 + l16) * 40 + quad * 8]);
        #pragma unroll
        for (int nt = 0; nt < 4; ++nt) {
            bf16x8 bf = *reinterpret_cast<const bf16x8*>(&Bs[(nt * 16 + l16) * 40 + quad * 8]);
            acc[nt] = __builtin_amdgcn_mfma_f32_16x16x32_bf16(af, bf, acc[nt], 0, 0, 0);
        }
    }
    #pragma unroll
    for (int nt = 0; nt < 4; ++nt)
        #pragma unroll
        for (int i = 0; i < 4; ++i) {
            int m = m0 + w * 16 + quad * 4 + i;
            int n = n0 + nt * 16 + l16;
            if (mode == 0) {
                C[(size_t)m * ldc + n] = acc[nt][i];
            } else {
                int bidx = (((n & 63) << 6) | (n >> 6));
                float v = acc[nt][i] + bias[bidx];
                v = fmaxf(v, 0.0f);
                Cb[(size_t)m * ldc + n] = f2bf(v);
            }
        }
}

// cmat GEMM with A = f32 tgw (cols 64..2112), conversion fused into A-staging
static __device__ __forceinline__ void gemm_tgwa_core(
    const float* __restrict__ tgw,
    const unsigned short* __restrict__ B,   // nattb [64,2048]
    float* __restrict__ C, long strideCz,
    int kchunk, int bm, int bz,
    unsigned short* __restrict__ As, unsigned short* __restrict__ Bs)
{
    const int t = threadIdx.x;
    const int w = t >> 6, lane = t & 63, l16 = lane & 15, quad = lane >> 4;
    const int m0 = bm * 64;
    const int kb0 = bz * kchunk;
    const int r = t >> 2, koff = (t & 3) * 8;
    C += (size_t)bz * strideCz;

    const float* arow = tgw + (size_t)(m0 + r) * 2112 + 64 + koff;
    const unsigned short* brow = B + (size_t)r * 2048 + koff;
    bf16x8 av = cvt8(arow + kb0);
    bf16x8 bv = *reinterpret_cast<const bf16x8*>(brow + kb0);

    f32x4 acc[4] = {};
    for (int kb = kb0; kb < kb0 + kchunk; kb += 32) {
        __syncthreads();
        *reinterpret_cast<bf16x8*>(&As[r * 40 + koff]) = av;
        *reinterpret_cast<bf16x8*>(&Bs[r * 40 + koff]) = bv;
        if (kb + 32 < kb0 + kchunk) {
            av = cvt8(arow + kb + 32);
            bv = *reinterpret_cast<const bf16x8*>(brow + kb + 32);
        }
        __syncthreads();
        bf16x8 af = *reinterpret_cast<const bf16x8*>(&As[(w * 16 + l16) * 40 + quad * 8]);
        #pragma unroll
        for (int nt = 0; nt < 4; ++nt) {
            bf16x8 bf = *reinterpret_cast<const bf16x8*>(&Bs[(nt * 16 + l16) * 40 + quad * 8]);
            acc[nt] = __builtin_amdgcn_mfma_f32_16x16x32_bf16(af, bf, acc[nt], 0, 0, 0);
        }
    }
    #pragma unroll
    for (int nt = 0; nt < 4; ++nt)
        #pragma unroll
        for (int i = 0; i < 4; ++i) {
            int m = m0 + w * 16 + quad * 4 + i;
            int n = nt * 16 + l16;
            C[(size_t)m * 64 + n] = acc[nt][i];
        }
}

static __device__ __forceinline__ void gemm_fa_core(
    const float* __restrict__ Ap, int lda, long apstride, int nparts,
    const float* __restrict__ abias,
    const unsigned short* __restrict__ B, int ldb,
    float* __restrict__ C, unsigned short* __restrict__ Cb,
    int ldc, long strideCz, const float* __restrict__ bias,
    int mode, int kchunk, int bn, int bm, int bz,
    unsigned short* __restrict__ As, unsigned short* __restrict__ Bs)
{
    const int t = threadIdx.x;
    const int w = t >> 6, lane = t & 63, l16 = lane & 15, quad = lane >> 4;
    const int n0 = bn * 64, m0 = bm * 64;
    const int kb0 = bz * kchunk;
    const int r = t >> 2, koff = (t & 3) * 8;
    if (mode == 0) C += (size_t)bz * strideCz;

    f32x4 acc[4] = {};
    for (int kb = kb0; kb < kb0 + kchunk; kb += 32) {
        float a8[8];
        {
            const float* base = &Ap[(size_t)(m0 + r) * lda + kb + koff];
            float4 s0 = *reinterpret_cast<const float4*>(base);
            float4 s1 = *reinterpret_cast<const float4*>(base + 4);
            for (int j = 1; j < nparts; ++j) {
                const float* pj = base + (size_t)j * apstride;
                float4 p0 = *reinterpret_cast<const float4*>(pj);
                float4 p1 = *reinterpret_cast<const float4*>(pj + 4);
                s0.x += p0.x; s0.y += p0.y; s0.z += p0.z; s0.w += p0.w;
                s1.x += p1.x; s1.y += p1.y; s1.z += p1.z; s1.w += p1.w;
            }
            float4 b0 = *reinterpret_cast<const float4*>(&abias[kb + koff]);
            float4 b1 = *reinterpret_cast<const float4*>(&abias[kb + koff + 4]);
            a8[0] = fmaxf(s0.x + b0.x, 0.0f); a8[1] = fmaxf(s0.y + b0.y, 0.0f);
            a8[2] = fmaxf(s0.z + b0.z, 0.0f); a8[3] = fmaxf(s0.w + b0.w, 0.0f);
            a8[4] = fmaxf(s1.x + b1.x, 0.0f); a8[5] = fmaxf(s1.y + b1.y, 0.0f);
            a8[6] = fmaxf(s1.z + b1.z, 0.0f); a8[7] = fmaxf(s1.w + b1.w, 0.0f);
        }
        bf16x8 bv = *reinterpret_cast<const bf16x8*>(&B[(size_t)(n0 + r) * ldb + kb + koff]);
        __syncthreads();
        ushort4 lo, hi;
        lo.x = f2bf(a8[0]); lo.y = f2bf(a8[1]); lo.z = f2bf(a8[2]); lo.w = f2bf(a8[3]);
        hi.x = f2bf(a8[4]); hi.y = f2bf(a8[5]); hi.z = f2bf(a8[6]); hi.w = f2bf(a8[7]);
        *reinterpret_cast<ushort4*>(&As[r * 40 + koff]) = lo;
        *reinterpret_cast<ushort4*>(&As[r * 40 + koff + 4]) = hi;
        *reinterpret_cast<bf16x8*>(&Bs[r * 40 + koff]) = bv;
        __syncthreads();
        bf16x8 af = *reinterpret_cast<const bf16x8*>(&As[(w * 16 + l16) * 40 + quad * 8]);
        #pragma unroll
        for (int nt = 0; nt < 4; ++nt) {
            bf16x8 bf = *reinterpret_cast<const bf16x8*>(&Bs[(nt * 16 + l16) * 40 + quad * 8]);
            acc[nt] = __builtin_amdgcn_mfma_f32_16x16x32_bf16(af, bf, acc[nt], 0, 0, 0);
        }
    }
    #pragma unroll
    for (int nt = 0; nt < 4; ++nt)
        #pragma unroll
        for (int i = 0; i < 4; ++i) {
            int m = m0 + w * 16 + quad * 4 + i;
            int n = n0 + nt * 16 + l16;
            if (mode == 0) {
                C[(size_t)m * ldc + n] = acc[nt][i];
            } else {
                int bidx = (((n & 63) << 6) | (n >> 6));
                float v = acc[nt][i] + bias[bidx];
                v = fmaxf(v, 0.0f);
                Cb[(size_t)m * ldc + n] = f2bf(v);
            }
        }
}

static __device__ __forceinline__ void nt1f_phase(
    int b, unsigned short* __restrict__ smemu,
    const unsigned short* __restrict__ hbT, const unsigned short* __restrict__ Wb,
    unsigned short* __restrict__ nt1b)
{
    unsigned short* HtT   = smemu;             // [64][72]
    unsigned short* nt1_s = smemu + 64 * 72;   // [64][72]
    const int t = threadIdx.x;
    const int w = t >> 6, lane = t & 63, l16 = lane & 15, quad = lane >> 4;

    const unsigned short* src = hbT + (size_t)b * 4096;
    #pragma unroll
    for (int j = 0; j < 2; ++j) {
        int c = t + j * 256;
        *reinterpret_cast<bf16x8*>(&HtT[(c >> 3) * 72 + (c & 7) * 8]) =
            *reinterpret_cast<const bf16x8*>(&src[c * 8]);
    }
    __syncthreads();

    bf16x8 aW[2];
    #pragma unroll
    for (int h = 0; h < 2; ++h)
        aW[h] = *reinterpret_cast<const bf16x8*>(&Wb[(w * 16 + l16) * 64 + h * 32 + quad * 8]);
    #pragma unroll
    for (int dt = 0; dt < 4; ++dt) {
        f32x4 acc = {0.0f, 0.0f, 0.0f, 0.0f};
        #pragma unroll
        for (int h = 0; h < 2; ++h) {
            bf16x8 bf = *reinterpret_cast<const bf16x8*>(
                &HtT[(dt * 16 + l16) * 72 + h * 32 + quad * 8]);
            acc = __builtin_amdgcn_mfma_f32_16x16x32_bf16(aW[h], bf, acc, 0, 0, 0);
        }
        #pragma unroll
        for (int i = 0; i < 4; ++i)
            nt1_s[(w * 16 + quad * 4 + i) * 72 + dt * 16 + l16] = f2bf(acc[i]);
    }
    __syncthreads();
    #pragma unroll
    for (int j = 0; j < 2; ++j) {
        int c = t + j * 256;
        *reinterpret_cast<bf16x8*>(&nt1b[(size_t)b * 4096 + c * 8]) =
            *reinterpret_cast<const bf16x8*>(&nt1_s[(c >> 3) * 72 + (c & 7) * 8]);
    }
}

// ---------------------------------------------------------------------------
// Uber kernels
// ---------------------------------------------------------------------------
__global__ __launch_bounds__(256) void uber1(   // conv (vectorized) + coef
    const float* x, const float* fcinW, const float* fc1W, const float* ntW,
    const float* out1W, const float* tgw,
    unsigned short* xb, unsigned short* fcinWb, unsigned short* fc1Wb,
    unsigned short* Wb, unsigned short* out1WbT, unsigned short* Gb,
    const float* coef_m, const float* cW, const float* cB, const float* attW,
    float* cfs)
{
    __shared__ __align__(16) float smemf[1280];
    int bx = blockIdx.x;
    if (bx < CONV_BLOCKS)
        conv_phase(bx, x, fcinW, fc1W, ntW, out1W, tgw,
                   xb, fcinWb, fc1Wb, Wb, out1WbT, Gb);
    else
        coef_phase(bx - CONV_BLOCKS, smemf, coef_m, cW, cB, attW, cfs);
}

__global__ __launch_bounds__(256) void uber2(   // fc_in GEMM (ksplit 8) + att
    const unsigned short* xb, const unsigned short* fcinWb, float* h1p,
    const float* cfs, const float* oattW, float* att)
{
    __shared__ __align__(16) float smemf[2592];
    int bx = blockIdx.x;
    if (bx < 1024) {
        unsigned short* As = (unsigned short*)smemf;
        gemm_core(xb, 2048, fcinWb, 2048, h1p, nullptr, 1024, 524288L,
                  nullptr, 0, 256, bx & 15, (bx >> 4) & 7, bx >> 7, As, As + 2560);
    } else {
        int b2 = bx - 1024;
        att_phase(b2 & 63, b2 >> 6, smemf, cfs, oattW, att);
    }
}

__global__ __launch_bounds__(256) void uber3(   // fc1 GEMM(fa, nparts=8) + natt
    const float* h1p, const float* fc_in_b, const unsigned short* fc1Wb,
    float* h2p,
    const float* ntW, const float* att, unsigned short* nattb)
{
    __shared__ __align__(16) float smemf[5248];
    int bx = blockIdx.x;
    if (bx < 64) {
        unsigned short* As = (unsigned short*)smemf;
        gemm_fa_core(h1p, 1024, 524288L, 8, fc_in_b, fc1Wb, 1024,
                     h2p, nullptr, 128, 65536L, nullptr, 0, 256,
                     bx & 1, (bx >> 1) & 7, bx >> 4, As, As + 2560);
    } else {
        natt_phase(bx - 64, smemf, ntW, att, nattb);
    }
}

__global__ __launch_bounds__(256) void uber4(   // out1 GEMM(fa) + cmat GEMM (ksplit 16)
    const float* h2p, const float* fc1_b, const unsigned short* out1WbT,
    unsigned short* hbT, const float* out1_b,
    const float* tgw, const unsigned short* nattb, float* cpT)
{
    __shared__ __align__(16) float smemf[2560];
    unsigned short* As = (unsigned short*)smemf;
    int bx = blockIdx.x;
    if (bx < 512) {
        gemm_fa_core(h2p, 128, 65536L, 4, fc1_b, out1WbT, 128,
                     nullptr, hbT, 4096, 0L, out1_b, 2, 128,
                     bx & 63, bx >> 6, 0, As, As + 2560);
    } else {
        int b2 = bx - 512;   // [0,528): m in [0,33), z in [0,16)
        gemm_tgwa_core(tgw, nattb, cpT, 135168L, 128,
                       b2 % 33, b2 / 33, As, As + 2560);
    }
}

__global__ __launch_bounds__(256) void uber5(   // nt1f + cmat reduce (nparts=16)
    const unsigned short* hbT, const unsigned short* Wb, unsigned short* nt1b,
    const float* cpT, float* cmatT)
{
    __shared__ __align__(16) unsigned short smemu[2 * 64 * 72];
    int bx = blockIdx.x;
    if (bx < 512) {
        nt1f_phase(bx, smemu, hbT, Wb, nt1b);
    } else {
        int i = (bx - 512) * 256 + threadIdx.x;   // 528*256 = 135168 exact
        float a = 0.0f;
        #pragma unroll
        for (int j = 0; j < 16; ++j) a += cpT[i + (long)j * 135168L];
        cmatT[i] = a;
    }
}

// ---------------------------------------------------------------------------
// Final kernel, e-persistent / b-streaming: grid (33, 32), 16 b-rows/block.
// ---------------------------------------------------------------------------
__global__ __launch_bounds__(256) void final_eblk(
    const unsigned short* __restrict__ nt1b, // [512][64][64] bf16
    const unsigned short* __restrict__ Gb,   // [2112,64] bf16
    const float* __restrict__ cmatT,  // [2112,64]
    const float* __restrict__ outW,   // [2112]
    float* __restrict__ zpart)        // [33][512][64]
{
    __shared__ __align__(16) unsigned short nls[2][64 * 72];
    __shared__ float zs[2][4][64];
    const int t = threadIdx.x;
    const int w = t >> 6, lane = t & 63, l16 = lane & 15, quad = lane >> 4;
    const int eb = blockIdx.x;
    const int b0 = blockIdx.y * 16;
    const int ew = eb * 64 + w * 16;

    bf16x8 ga[2];
    #pragma unroll
    for (int h = 0; h < 2; ++h)
        ga[h] = *reinterpret_cast<const bf16x8*>(
            &Gb[(size_t)(ew + l16) * 64 + h * 32 + quad * 8]);
    float cm[4][4];
    #pragma unroll
    for (int nt = 0; nt < 4; ++nt)
        #pragma unroll
        for (int i = 0; i < 4; ++i)
            cm[nt][i] = cmatT[(size_t)(ew + quad * 4 + i) * 64 + nt * 16 + l16];
    float wv[4];
    #pragma unroll
    for (int i = 0; i < 4; ++i) wv[i] = outW[ew + quad * 4 + i];

    const int c0 = t, c1 = t + 256;
    bf16x8 v0 = *reinterpret_cast<const bf16x8*>(&nt1b[(size_t)b0 * 4096 + c0 * 8]);
    bf16x8 v1 = *reinterpret_cast<const bf16x8*>(&nt1b[(size_t)b0 * 4096 + c1 * 8]);
    *reinterpret_cast<bf16x8*>(&nls[0][(c0 >> 3) * 72 + (c0 & 7) * 8]) = v0;
    *reinterpret_cast<bf16x8*>(&nls[0][(c1 >> 3) * 72 + (c1 & 7) * 8]) = v1;
    __syncthreads();

    int cur = 0;
    for (int bi = 0; bi < 16; ++bi) {
        if (bi < 15) {
            v0 = *reinterpret_cast<const bf16x8*>(
                &nt1b[(size_t)(b0 + bi + 1) * 4096 + c0 * 8]);
            v1 = *reinterpret_cast<const bf16x8*>(
                &nt1b[(size_t)(b0 + bi + 1) * 4096 + c1 * 8]);
        }
        if (bi > 0 && t < 64) {
            const float* z = &zs[(bi - 1) & 1][0][0];
            zpart[((size_t)eb * 512 + b0 + bi - 1) * 64 + t] =
                z[t] + z[64 + t] + z[128 + t] + z[192 + t];
        }
        float zo[4] = {0.0f, 0.0f, 0.0f, 0.0f};
        #pragma unroll
        for (int nt = 0; nt < 4; ++nt) {
            bf16x8 bf0 = *reinterpret_cast<const bf16x8*>(
                &nls[cur][(nt * 16 + l16) * 72 + quad * 8]);
            bf16x8 bf1 = *reinterpret_cast<const bf16x8*>(
                &nls[cur][(nt * 16 + l16) * 72 + 32 + quad * 8]);
            f32x4 acc = {cm[nt][0], cm[nt][1], cm[nt][2], cm[nt][3]};
            acc = __builtin_amdgcn_mfma_f32_16x16x32_bf16(ga[0], bf0, acc, 0, 0, 0);
            acc = __builtin_amdgcn_mfma_f32_16x16x32_bf16(ga[1], bf1, acc, 0, 0, 0);
            #pragma unroll
            for (int i = 0; i < 4; ++i)
                zo[nt] += __builtin_amdgcn_rcpf(1.0f + __expf(-acc[i])) * wv[i];
        }
        #pragma unroll
        for (int nt = 0; nt < 4; ++nt) {
            zo[nt] += __shfl_xor(zo[nt], 16, 64);
            zo[nt] += __shfl_xor(zo[nt], 32, 64);
        }
        if (quad == 0) {
            #pragma unroll
            for (int nt = 0; nt < 4; ++nt)
                zs[bi & 1][w][nt * 16 + l16] = zo[nt];
        }
        if (bi < 15) {
            *reinterpret_cast<bf16x8*>(&nls[1 - cur][(c0 >> 3) * 72 + (c0 & 7) * 8]) = v0;
            *reinterpret_cast<bf16x8*>(&nls[1 - cur][(c1 >> 3) * 72 + (c1 & 7) * 8]) = v1;
        }
        __syncthreads();
        cur ^= 1;
    }
    if (t < 64) {   // tail: b0+15 (15&1 = 1)
        const float* z = &zs[1][0][0];
        zpart[((size_t)eb * 512 + b0 + 15) * 64 + t] =
            z[t] + z[64 + t] + z[128 + t] + z[192 + t];
    }
}

// out[i] = prelu( sum_z zpart[z][i] + outB )
__global__ __launch_bounds__(256) void finish_kernel(
    const float* __restrict__ zpart, const float* __restrict__ outB,
    const float* __restrict__ preluA, float* __restrict__ out)
{
    int i = blockIdx.x * 256 + threadIdx.x;  // < 32768
    float z = 0.0f;
    for (int j = 0; j < 33; ++j) z += zpart[(size_t)j * 32768 + i];
    z += outB[0];
    float pa = preluA[0];
    out[i] = (z >= 0.0f) ? z : pa * z;
}

extern "C" void kernel_launch(void* const* d_in, const int* in_sizes, int n_in,
                              void* d_out, int out_size, void* d_ws, size_t ws_size,
                              hipStream_t stream)
{
    const float* x       = (const float*)d_in[0];
    const float* fc_in_W = (const float*)d_in[1];
    const float* fc_in_b = (const float*)d_in[2];
    const float* fc1_W   = (const float*)d_in[3];
    const float* fc1_b   = (const float*)d_in[4];
    const float* out1_W  = (const float*)d_in[5];
    const float* out1_b  = (const float*)d_in[6];
    const float* cW      = (const float*)d_in[7];
    const float* cB      = (const float*)d_in[8];
    const float* cattW   = (const float*)d_in[9];
    const float* oattW   = (const float*)d_in[10];
    const float* ntW     = (const float*)d_in[11];
    const float* tgw     = (const float*)d_in[12];
    const float* outW    = (const float*)d_in[13];
    const float* outB    = (const float*)d_in[14];
    const float* preluA  = (const float*)d_in[15];
    const float* coef_m  = (const float*)d_in[16];
    float* out = (float*)d_out;
    float* ws  = (float*)d_ws;

    // workspace layout (float offsets) — NO aliasing (ws is >=268 MB)
    unsigned short* xb      = (unsigned short*)(ws + 0);          // 524,288 f
    unsigned short* fcinWb  = (unsigned short*)(ws + 524288);     // 1,048,576 f
    unsigned short* fc1Wb   = (unsigned short*)(ws + 1572864);    // 65,536 f
    unsigned short* Wb      = (unsigned short*)(ws + 1638400);    // 2,048 f
    unsigned short* out1WbT = (unsigned short*)(ws + 1640448);    // 262,144 f
    unsigned short* Gb      = (unsigned short*)(ws + 1902592);    // 67,584 f
    float*          cfs     = ws + 1970176;                       // 131,072 f
    float*          att     = ws + 2101248;                       // 131,072 f
    unsigned short* nattb   = (unsigned short*)(ws + 2232320);    // 65,536 f
    float*          h1p     = ws + 2297856;                       // 8*524,288 f
    float*          h2p     = ws + 6492160;                       // 4*65,536 f
    unsigned short* hbT     = (unsigned short*)(ws + 6754304);    // 1,048,576 f
    float*          cpT     = ws + 7802880;                       // 16*135,168 f
    float*          cmatT   = ws + 9965568;                       // 135,168 f
    unsigned short* nt1b    = (unsigned short*)(ws + 10100736);   // 1,048,576 f
    float*          zpart   = ws + 11149312;                      // 1,081,344 f
    // total 12,230,656 floats (~48.9 MB)

    // L1: conversions (vectorized) + coef
    uber1<<<CONV_BLOCKS + 1024, 256, 0, stream>>>(
        x, fc_in_W, fc1_W, ntW, out1_W, tgw,
        xb, fcinWb, fc1Wb, Wb, out1WbT, Gb,
        coef_m, cW, cB, cattW, cfs);
    // L2: fc_in GEMM (ksplit 8) + att
    uber2<<<1536, 256, 0, stream>>>(xb, fcinWb, h1p, cfs, oattW, att);
    // L3: fc1 GEMM(fa, nparts=8) + natt
    uber3<<<192, 256, 0, stream>>>(h1p, fc_in_b, fc1Wb, h2p, ntW, att, nattb);
    // L4: out1 GEMM(fa) + cmat GEMM (ksplit 16)
    uber4<<<1040, 256, 0, stream>>>(h2p, fc1_b, out1WbT, hbT, out1_b,
                                    tgw, nattb, cpT);
    // L5: nt1f + cmat reduce (nparts=16)
    uber5<<<1040, 256, 0, stream>>>(hbT, Wb, nt1b, cpT, cmatT);
    // L6: final, L7: finish
    final_eblk<<<dim3(33, 32), 256, 0, stream>>>(nt1b, Gb, cmatT, outW, zpart);
    finish_kernel<<<128, 256, 0, stream>>>(zpart, outB, preluA, out);
}

// Round 14
// 193.937 us; speedup vs baseline: 4.2768x; 1.0222x over previous
//
#include <hip/hip_runtime.h>
#include <math.h>

typedef __attribute__((ext_vector_type(8))) short bf16x8;
typedef __attribute__((ext_vector_type(4))) float f32x4;

static __device__ __forceinline__ float fast_elu(float x) {
    return x > 0.0f ? x : __expf(x) - 1.0f;
}

static __device__ __forceinline__ unsigned short f2bf(float f) {
    unsigned int u = __float_as_uint(f);
    unsigned int r = (u + 0x7FFFu + ((u >> 16) & 1u)) >> 16;
    return (unsigned short)r;
}

static __device__ __forceinline__ bf16x8 cvt8(const float* __restrict__ s) {
    float4 a = *reinterpret_cast<const float4*>(s);
    float4 b = *reinterpret_cast<const float4*>(s + 4);
    bf16x8 r;
    r[0] = (short)f2bf(a.x); r[1] = (short)f2bf(a.y);
    r[2] = (short)f2bf(a.z); r[3] = (short)f2bf(a.w);
    r[4] = (short)f2bf(b.x); r[5] = (short)f2bf(b.y);
    r[6] = (short)f2bf(b.z); r[7] = (short)f2bf(b.w);
    return r;
}

// conv segments in 8-element units (vectorized)
#define S0 131072    // xb      [512,2048 pad from 2000]
#define S1 393216    // fcinWb  [1024,2048 pad]
#define S2 409600    // fc1Wb   [128,1024]
#define S3 410112    // Wb      [64,64]
#define S4 475648    // out1WbT [4096,128] row-permuted
#define S5 492544    // Gb      [2112,64] = tgw cols 0:64
#define CONV_BLOCKS 1924   // S5/256

// ---------------------------------------------------------------------------
// Phase device functions (verbatim from R10)
// ---------------------------------------------------------------------------
static __device__ __forceinline__ void conv_phase(
    int bx,
    const float* __restrict__ x, const float* __restrict__ fcinW,
    const float* __restrict__ fc1W, const float* __restrict__ ntW,
    const float* __restrict__ out1W, const float* __restrict__ tgw,
    unsigned short* __restrict__ xb, unsigned short* __restrict__ fcinWb,
    unsigned short* __restrict__ fc1Wb, unsigned short* __restrict__ Wb,
    unsigned short* __restrict__ out1WbT, unsigned short* __restrict__ Gb)
{
    int u = bx * 256 + threadIdx.x;
    if (u < S0) {
        int r = u >> 8, c = u & 255;
        bf16x8 v;
        if (c < 250) v = cvt8(&x[(size_t)r * 2000 + c * 8]);
        else { bf16x8 z = {0,0,0,0,0,0,0,0}; v = z; }
        *reinterpret_cast<bf16x8*>(&xb[(size_t)r * 2048 + c * 8]) = v;
    } else if (u < S1) {
        int i = u - S0;
        int r = i >> 8, c = i & 255;
        bf16x8 v;
        if (c < 250) v = cvt8(&fcinW[(size_t)r * 2000 + c * 8]);
        else { bf16x8 z = {0,0,0,0,0,0,0,0}; v = z; }
        *reinterpret_cast<bf16x8*>(&fcinWb[(size_t)r * 2048 + c * 8]) = v;
    } else if (u < S2) {
        int i8 = (u - S1) * 8;
        *reinterpret_cast<bf16x8*>(&fc1Wb[i8]) = cvt8(&fc1W[i8]);
    } else if (u < S3) {
        int i8 = (u - S2) * 8;
        *reinterpret_cast<bf16x8*>(&Wb[i8]) = cvt8(&ntW[i8]);
    } else if (u < S4) {
        int i = u - S3;
        int n = i >> 4, kc = i & 15;
        int d = n >> 6, p = n & 63;
        *reinterpret_cast<bf16x8*>(&out1WbT[(size_t)n * 128 + kc * 8]) =
            cvt8(&out1W[(size_t)((p << 6) | d) * 128 + kc * 8]);
    } else if (u < S5) {
        int i = u - S4;
        int e = i >> 3, c = i & 7;
        *reinterpret_cast<bf16x8*>(&Gb[(size_t)e * 64 + c * 8]) =
            cvt8(&tgw[(size_t)e * 2112 + c * 8]);
    }
}

static __device__ __forceinline__ void coef_phase(
    int bx, float* __restrict__ smemf,
    const float* __restrict__ coef_m, const float* __restrict__ cW,
    const float* __restrict__ cB, const float* __restrict__ attW,
    float* __restrict__ cfs)
{
    float* cf_s = smemf;            // [4][256]
    float* part = smemf + 1024;     // [4][64]
    const int t = threadIdx.x;
    const int wv = t >> 6, lane = t & 63;
    const int xy = bx * 4 + wv;
    float ls = 0.0f;
    #pragma unroll
    for (int i = 0; i < 4; ++i) {
        int idx = i * 64 + lane;
        int f = idx >> 5;
        float v = fast_elu(coef_m[xy * 8 + f] * cW[idx] + cB[idx]);
        cf_s[wv * 256 + idx] = v;
        ls += __expf(fast_elu(v));
    }
    #pragma unroll
    for (int m = 1; m < 64; m <<= 1) ls += __shfl_xor(ls, m, 64);
    __syncthreads();
    const float rs = __builtin_amdgcn_rcpf(ls);
    const int g = lane & 31, fg = lane >> 5;
    float acc = 0.0f;
    for (int f = fg * 4; f < fg * 4 + 4; ++f) {
        float lin = 0.0f;
        #pragma unroll
        for (int h = 0; h < 32; h += 4) {
            float4 Lv = *reinterpret_cast<const float4*>(&cf_s[wv * 256 + f * 32 + h]);
            float4 Wv = *reinterpret_cast<const float4*>(&attW[f * 1024 + g * 32 + h]);
            lin += Lv.x * Wv.x + Lv.y * Wv.y + Lv.z * Wv.z + Lv.w * Wv.w;
        }
        float e = __expf(fast_elu(cf_s[wv * 256 + f * 32 + g]));
        acc += fast_elu(e * lin * rs);
    }
    part[wv * 64 + lane] = acc;
    __syncthreads();
    if (lane < 32) {
        float tot = part[wv * 64 + lane] + part[wv * 64 + lane + 32];
        cfs[xy * 32 + lane] = fast_elu(tot * 0.125f);
    }
}

static __device__ __forceinline__ void att_phase(
    int o, int ic, float* __restrict__ smemf,
    const float* __restrict__ cfs, const float* __restrict__ oattW,
    float* __restrict__ att)
{
    float* L    = smemf;          // 2048
    float* red  = smemf + 2048;   // 256
    float* csum = smemf + 2304;   // 32
    const int t = threadIdx.x;
    #pragma unroll
    for (int j = 0; j < 8; ++j) L[t + 256 * j] = cfs[o * 2048 + t + 256 * j];
    __syncthreads();
    {
        int h = t & 31, ig = t >> 5;
        float ps = 0.0f;
        for (int i = ig * 8; i < ig * 8 + 8; ++i) ps += __expf(fast_elu(L[i * 32 + h]));
        red[t] = ps;
        __syncthreads();
        if (t < 32) {
            float cs = 0.0f;
            #pragma unroll
            for (int j = 0; j < 8; ++j) cs += red[j * 32 + t];
            csum[t] = cs;
        }
        __syncthreads();
    }
    int idx = ic * 256 + t;
    int i = idx >> 5, g = idx & 31;
    float lin2 = 0.0f;
    #pragma unroll
    for (int h = 0; h < 32; h += 4) {
        float4 Lv = *reinterpret_cast<const float4*>(&L[i * 32 + h]);
        float4 Wv = *reinterpret_cast<const float4*>(&oattW[i * 1024 + g * 32 + h]);
        lin2 += Lv.x * Wv.x + Lv.y * Wv.y + Lv.z * Wv.z + Lv.w * Wv.w;
    }
    float p2 = __expf(fast_elu(L[idx])) * __builtin_amdgcn_rcpf(csum[g]);
    att[o * 2048 + idx] = p2 * lin2;
}

static __device__ __forceinline__ void natt_phase(
    int bx, float* __restrict__ smemf,
    const float* __restrict__ ntW, const float* __restrict__ att,
    unsigned short* __restrict__ nattb)
{
    float* ntW_s = smemf;             // 64*65
    float* att_s = smemf + 64 * 65;   // 64*17
    const int t = threadIdx.x;
    const int d0 = bx * 16;
    #pragma unroll
    for (int j = 0; j < 16; ++j) {
        int idx = t + 256 * j;
        ntW_s[(idx >> 6) * 65 + (idx & 63)] = ntW[idx];
    }
    #pragma unroll
    for (int j = 0; j < 4; ++j) {
        int idx = t + 256 * j;
        int p = idx >> 4, dd = idx & 15;
        att_s[p * 17 + dd] = att[p * 2048 + d0 + dd];
    }
    __syncthreads();
    const int dd = t & 15, ob = (t >> 4) * 4;
    float acc[4] = {0.0f, 0.0f, 0.0f, 0.0f};
    for (int p = 0; p < 64; ++p) {
        float av = att_s[p * 17 + dd];
        #pragma unroll
        for (int i = 0; i < 4; ++i) acc[i] += ntW_s[(ob + i) * 65 + p] * av;
    }
    #pragma unroll
    for (int i = 0; i < 4; ++i)
        nattb[(ob + i) * 2048 + d0 + dd] = f2bf(acc[i]);
}

static __device__ __forceinline__ void gemm_core(
    const unsigned short* __restrict__ A, int lda,
    const unsigned short* __restrict__ B, int ldb,
    float* __restrict__ C, unsigned short* __restrict__ Cb,
    int ldc, long strideCz, const float* __restrict__ bias,
    int mode, int kchunk, int bn, int bm, int bz,
    unsigned short* __restrict__ As, unsigned short* __restrict__ Bs)
{
    const int t = threadIdx.x;
    const int w = t >> 6, lane = t & 63, l16 = lane & 15, quad = lane >> 4;
    const int n0 = bn * 64, m0 = bm * 64;
    const int kb0 = bz * kchunk;
    const int r = t >> 2, koff = (t & 3) * 8;
    if (mode == 0) C += (size_t)bz * strideCz;

    const size_t arow = (size_t)(m0 + r) * lda + koff;
    const size_t brow = (size_t)(n0 + r) * ldb + koff;
    bf16x8 av = *reinterpret_cast<const bf16x8*>(&A[arow + kb0]);
    bf16x8 bv = *reinterpret_cast<const bf16x8*>(&B[brow + kb0]);

    f32x4 acc[4] = {};
    for (int kb = kb0; kb < kb0 + kchunk; kb += 32) {
        __syncthreads();
        *reinterpret_cast<bf16x8*>(&As[r * 40 + koff]) = av;
        *reinterpret_cast<bf16x8*>(&Bs[r * 40 + koff]) = bv;
        if (kb + 32 < kb0 + kchunk) {
            av = *reinterpret_cast<const bf16x8*>(&A[arow + kb + 32]);
            bv = *reinterpret_cast<const bf16x8*>(&B[brow + kb + 32]);
        }
        __syncthreads();
        bf16x8 af = *reinterpret_cast<const bf16x8*>(&As[(w * 16 + l16) * 40 + quad * 8]);
        #pragma unroll
        for (int nt = 0; nt < 4; ++nt) {
            bf16x8 bf = *reinterpret_cast<const bf16x8*>(&Bs[(nt * 16 + l16) * 40 + quad * 8]);
            acc[nt] = __builtin_amdgcn_mfma_f32_16x16x32_bf16(af, bf, acc[nt], 0, 0, 0);
        }
    }
    #pragma unroll
    for (int nt = 0; nt < 4; ++nt)
        #pragma unroll
        for (int i = 0; i < 4; ++i) {
            int m = m0 + w * 16 + quad * 4 + i;
            int n = n0 + nt * 16 + l16;
            if (mode == 0) {
                C[(size_t)m * ldc + n] = acc[nt][i];
            } else {
                int bidx = (((n & 63) << 6) | (n >> 6));
                float v = acc[nt][i] + bias[bidx];
                v = fmaxf(v, 0.0f);
                Cb[(size_t)m * ldc + n] = f2bf(v);
            }
        }
}

// cmat GEMM with A = f32 tgw (cols 64..2112), conversion fused into A-staging
static __device__ __forceinline__ void gemm_tgwa_core(
    const float* __restrict__ tgw,
    const unsigned short* __restrict__ B,   // nattb [64,2048]
    float* __restrict__ C, long strideCz,
    int kchunk, int bm, int bz,
    unsigned short* __restrict__ As, unsigned short* __restrict__ Bs)
{
    const int t = threadIdx.x;
    const int w = t >> 6, lane = t & 63, l16 = lane & 15, quad = lane >> 4;
    const int m0 = bm * 64;
    const int kb0 = bz * kchunk;
    const int r = t >> 2, koff = (t & 3) * 8;
    C += (size_t)bz * strideCz;

    const float* arow = tgw + (size_t)(m0 + r) * 2112 + 64 + koff;
    const unsigned short* brow = B + (size_t)r * 2048 + koff;
    bf16x8 av = cvt8(arow + kb0);
    bf16x8 bv = *reinterpret_cast<const bf16x8*>(brow + kb0);

    f32x4 acc[4] = {};
    for (int kb = kb0; kb < kb0 + kchunk; kb += 32) {
        __syncthreads();
        *reinterpret_cast<bf16x8*>(&As[r * 40 + koff]) = av;
        *reinterpret_cast<bf16x8*>(&Bs[r * 40 + koff]) = bv;
        if (kb + 32 < kb0 + kchunk) {
            av = cvt8(arow + kb + 32);
            bv = *reinterpret_cast<const bf16x8*>(brow + kb + 32);
        }
        __syncthreads();
        bf16x8 af = *reinterpret_cast<const bf16x8*>(&As[(w * 16 + l16) * 40 + quad * 8]);
        #pragma unroll
        for (int nt = 0; nt < 4; ++nt) {
            bf16x8 bf = *reinterpret_cast<const bf16x8*>(&Bs[(nt * 16 + l16) * 40 + quad * 8]);
            acc[nt] = __builtin_amdgcn_mfma_f32_16x16x32_bf16(af, bf, acc[nt], 0, 0, 0);
        }
    }
    #pragma unroll
    for (int nt = 0; nt < 4; ++nt)
        #pragma unroll
        for (int i = 0; i < 4; ++i) {
            int m = m0 + w * 16 + quad * 4 + i;
            int n = nt * 16 + l16;
            C[(size_t)m * 64 + n] = acc[nt][i];
        }
}

static __device__ __forceinline__ void gemm_fa_core(
    const float* __restrict__ Ap, int lda, long apstride, int nparts,
    const float* __restrict__ abias,
    const unsigned short* __restrict__ B, int ldb,
    float* __restrict__ C, unsigned short* __restrict__ Cb,
    int ldc, long strideCz, const float* __restrict__ bias,
    int mode, int kchunk, int bn, int bm, int bz,
    unsigned short* __restrict__ As, unsigned short* __restrict__ Bs)
{
    const int t = threadIdx.x;
    const int w = t >> 6, lane = t & 63, l16 = lane & 15, quad = lane >> 4;
    const int n0 = bn * 64, m0 = bm * 64;
    const int kb0 = bz * kchunk;
    const int r = t >> 2, koff = (t & 3) * 8;
    if (mode == 0) C += (size_t)bz * strideCz;

    f32x4 acc[4] = {};
    for (int kb = kb0; kb < kb0 + kchunk; kb += 32) {
        float a8[8];
        {
            const float* base = &Ap[(size_t)(m0 + r) * lda + kb + koff];
            float4 s0 = *reinterpret_cast<const float4*>(base);
            float4 s1 = *reinterpret_cast<const float4*>(base + 4);
            for (int j = 1; j < nparts; ++j) {
                const float* pj = base + (size_t)j * apstride;
                float4 p0 = *reinterpret_cast<const float4*>(pj);
                float4 p1 = *reinterpret_cast<const float4*>(pj + 4);
                s0.x += p0.x; s0.y += p0.y; s0.z += p0.z; s0.w += p0.w;
                s1.x += p1.x; s1.y += p1.y; s1.z += p1.z; s1.w += p1.w;
            }
            float4 b0 = *reinterpret_cast<const float4*>(&abias[kb + koff]);
            float4 b1 = *reinterpret_cast<const float4*>(&abias[kb + koff + 4]);
            a8[0] = fmaxf(s0.x + b0.x, 0.0f); a8[1] = fmaxf(s0.y + b0.y, 0.0f);
            a8[2] = fmaxf(s0.z + b0.z, 0.0f); a8[3] = fmaxf(s0.w + b0.w, 0.0f);
            a8[4] = fmaxf(s1.x + b1.x, 0.0f); a8[5] = fmaxf(s1.y + b1.y, 0.0f);
            a8[6] = fmaxf(s1.z + b1.z, 0.0f); a8[7] = fmaxf(s1.w + b1.w, 0.0f);
        }
        bf16x8 bv = *reinterpret_cast<const bf16x8*>(&B[(size_t)(n0 + r) * ldb + kb + koff]);
        __syncthreads();
        ushort4 lo, hi;
        lo.x = f2bf(a8[0]); lo.y = f2bf(a8[1]); lo.z = f2bf(a8[2]); lo.w = f2bf(a8[3]);
        hi.x = f2bf(a8[4]); hi.y = f2bf(a8[5]); hi.z = f2bf(a8[6]); hi.w = f2bf(a8[7]);
        *reinterpret_cast<ushort4*>(&As[r * 40 + koff]) = lo;
        *reinterpret_cast<ushort4*>(&As[r * 40 + koff + 4]) = hi;
        *reinterpret_cast<bf16x8*>(&Bs[r * 40 + koff]) = bv;
        __syncthreads();
        bf16x8 af = *reinterpret_cast<const bf16x8*>(&As[(w * 16 + l16) * 40 + quad * 8]);
        #pragma unroll
        for (int nt = 0; nt < 4; ++nt) {
            bf16x8 bf = *reinterpret_cast<const bf16x8*>(&Bs[(nt * 16 + l16) * 40 + quad * 8]);
            acc[nt] = __builtin_amdgcn_mfma_f32_16x16x32_bf16(af, bf, acc[nt], 0, 0, 0);
        }
    }
    #pragma unroll
    for (int nt = 0; nt < 4; ++nt)
        #pragma unroll
        for (int i = 0; i < 4; ++i) {
            int m = m0 + w * 16 + quad * 4 + i;
            int n = n0 + nt * 16 + l16;
            if (mode == 0) {
                C[(size_t)m * ldc + n] = acc[nt][i];
            } else {
                int bidx = (((n & 63) << 6) | (n >> 6));
                float v = acc[nt][i] + bias[bidx];
                v = fmaxf(v, 0.0f);
                Cb[(size_t)m * ldc + n] = f2bf(v);
            }
        }
}

static __device__ __forceinline__ void nt1f_phase(
    int b, unsigned short* __restrict__ smemu,
    const unsigned short* __restrict__ hbT, const unsigned short* __restrict__ Wb,
    unsigned short* __restrict__ nt1b)
{
    unsigned short* HtT   = smemu;             // [64][72]
    unsigned short* nt1_s = smemu + 64 * 72;   // [64][72]
    const int t = threadIdx.x;
    const int w = t >> 6, lane = t & 63, l16 = lane & 15, quad = lane >> 4;

    const unsigned short* src = hbT + (size_t)b * 4096;
    #pragma unroll
    for (int j = 0; j < 2; ++j) {
        int c = t + j * 256;
        *reinterpret_cast<bf16x8*>(&HtT[(c >> 3) * 72 + (c & 7) * 8]) =
            *reinterpret_cast<const bf16x8*>(&src[c * 8]);
    }
    __syncthreads();

    bf16x8 aW[2];
    #pragma unroll
    for (int h = 0; h < 2; ++h)
        aW[h] = *reinterpret_cast<const bf16x8*>(&Wb[(w * 16 + l16) * 64 + h * 32 + quad * 8]);
    #pragma unroll
    for (int dt = 0; dt < 4; ++dt) {
        f32x4 acc = {0.0f, 0.0f, 0.0f, 0.0f};
        #pragma unroll
        for (int h = 0; h < 2; ++h) {
            bf16x8 bf = *reinterpret_cast<const bf16x8*>(
                &HtT[(dt * 16 + l16) * 72 + h * 32 + quad * 8]);
            acc = __builtin_amdgcn_mfma_f32_16x16x32_bf16(aW[h], bf, acc, 0, 0, 0);
        }
        #pragma unroll
        for (int i = 0; i < 4; ++i)
            nt1_s[(w * 16 + quad * 4 + i) * 72 + dt * 16 + l16] = f2bf(acc[i]);
    }
    __syncthreads();
    #pragma unroll
    for (int j = 0; j < 2; ++j) {
        int c = t + j * 256;
        *reinterpret_cast<bf16x8*>(&nt1b[(size_t)b * 4096 + c * 8]) =
            *reinterpret_cast<const bf16x8*>(&nt1_s[(c >> 3) * 72 + (c & 7) * 8]);
    }
}

// ---------------------------------------------------------------------------
// Uber kernels (R10-exact configurations)
// ---------------------------------------------------------------------------
__global__ __launch_bounds__(256) void uber1(   // conv (vectorized) + coef
    const float* x, const float* fcinW, const float* fc1W, const float* ntW,
    const float* out1W, const float* tgw,
    unsigned short* xb, unsigned short* fcinWb, unsigned short* fc1Wb,
    unsigned short* Wb, unsigned short* out1WbT, unsigned short* Gb,
    const float* coef_m, const float* cW, const float* cB, const float* attW,
    float* cfs)
{
    __shared__ __align__(16) float smemf[1280];
    int bx = blockIdx.x;
    if (bx < CONV_BLOCKS)
        conv_phase(bx, x, fcinW, fc1W, ntW, out1W, tgw,
                   xb, fcinWb, fc1Wb, Wb, out1WbT, Gb);
    else
        coef_phase(bx - CONV_BLOCKS, smemf, coef_m, cW, cB, attW, cfs);
}

__global__ __launch_bounds__(256) void uber2(   // fc_in GEMM (ksplit 4) + att
    const unsigned short* xb, const unsigned short* fcinWb, float* h1p,
    const float* cfs, const float* oattW, float* att)
{
    __shared__ __align__(16) float smemf[2592];
    int bx = blockIdx.x;
    if (bx < 512) {
        unsigned short* As = (unsigned short*)smemf;
        gemm_core(xb, 2048, fcinWb, 2048, h1p, nullptr, 1024, 524288L,
                  nullptr, 0, 512, bx & 15, (bx >> 4) & 7, bx >> 7, As, As + 2560);
    } else {
        int b2 = bx - 512;
        att_phase(b2 & 63, b2 >> 6, smemf, cfs, oattW, att);
    }
}

__global__ __launch_bounds__(256) void uber3(   // fc1 GEMM(fa, nparts=4) + natt
    const float* h1p, const float* fc_in_b, const unsigned short* fc1Wb,
    float* h2p,
    const float* ntW, const float* att, unsigned short* nattb)
{
    __shared__ __align__(16) float smemf[5248];
    int bx = blockIdx.x;
    if (bx < 64) {
        unsigned short* As = (unsigned short*)smemf;
        gemm_fa_core(h1p, 1024, 524288L, 4, fc_in_b, fc1Wb, 1024,
                     h2p, nullptr, 128, 65536L, nullptr, 0, 256,
                     bx & 1, (bx >> 1) & 7, bx >> 4, As, As + 2560);
    } else {
        natt_phase(bx - 64, smemf, ntW, att, nattb);
    }
}

__global__ __launch_bounds__(256) void uber4(   // out1 GEMM(fa) + cmat GEMM (ksplit 8)
    const float* h2p, const float* fc1_b, const unsigned short* out1WbT,
    unsigned short* hbT, const float* out1_b,
    const float* tgw, const unsigned short* nattb, float* cpT)
{
    __shared__ __align__(16) float smemf[2560];
    unsigned short* As = (unsigned short*)smemf;
    int bx = blockIdx.x;
    if (bx < 512) {
        gemm_fa_core(h2p, 128, 65536L, 4, fc1_b, out1WbT, 128,
                     nullptr, hbT, 4096, 0L, out1_b, 2, 128,
                     bx & 63, bx >> 6, 0, As, As + 2560);
    } else {
        int b2 = bx - 512;   // [0,264): m in [0,33), z in [0,8)
        gemm_tgwa_core(tgw, nattb, cpT, 135168L, 256,
                       b2 % 33, b2 / 33, As, As + 2560);
    }
}

__global__ __launch_bounds__(256) void uber5(   // nt1f + cmat reduce (nparts=8)
    const unsigned short* hbT, const unsigned short* Wb, unsigned short* nt1b,
    const float* cpT, float* cmatT)
{
    __shared__ __align__(16) unsigned short smemu[2 * 64 * 72];
    int bx = blockIdx.x;
    if (bx < 512) {
        nt1f_phase(bx, smemu, hbT, Wb, nt1b);
    } else {
        int i = (bx - 512) * 256 + threadIdx.x;
        if (i < 135168) {
            float a = 0.0f;
            #pragma unroll
            for (int j = 0; j < 8; ++j) a += cpT[i + (long)j * 135168L];
            cmatT[i] = a;
        }
    }
}

// ---------------------------------------------------------------------------
// final_nb: barrier-free, LDS-free final. grid (33, 32), block 256 = 4 waves.
// Wave w owns o-slice [w*16,+16) and ALL 64 e of its e-block eb; streams 16
// b-rows. B-fragments read directly from nt1b (fragment-linear layout); G/cmat/
// outW for all 4 e-subtiles persistent in registers; next-b register prefetch.
// Each (eb,b,o) written by exactly one wave -> zpart[33][512][64], no overlap.
// ---------------------------------------------------------------------------
__global__ __launch_bounds__(256) void final_nb(
    const unsigned short* __restrict__ nt1b, // [512][64][64] bf16
    const unsigned short* __restrict__ Gb,   // [2112,64] bf16
    const float* __restrict__ cmatT,  // [2112,64]
    const float* __restrict__ outW,   // [2112]
    float* __restrict__ zpart)        // [33][512][64]
{
    const int t = threadIdx.x;
    const int w = t >> 6, lane = t & 63, l16 = lane & 15, quad = lane >> 4;
    const int eb = blockIdx.x;
    const int b0 = blockIdx.y * 16;
    const int o = w * 16 + l16;

    // persistent per-wave state for all 4 e-subtiles of this e-block
    bf16x8 ga[4][2];
    float cm[4][4], wv[4][4];
    #pragma unroll
    for (int et = 0; et < 4; ++et) {
        #pragma unroll
        for (int h = 0; h < 2; ++h)
            ga[et][h] = *reinterpret_cast<const bf16x8*>(
                &Gb[(size_t)(eb * 64 + et * 16 + l16) * 64 + h * 32 + quad * 8]);
        #pragma unroll
        for (int i = 0; i < 4; ++i) {
            int e = eb * 64 + et * 16 + quad * 4 + i;
            cm[et][i] = cmatT[(size_t)e * 64 + o];
            wv[et][i] = outW[e];
        }
    }

    // B-fragment base for this lane (o row, k = quad*8); rows advance by 4096
    const unsigned short* bbase = nt1b + (size_t)b0 * 4096 + o * 64 + quad * 8;
    bf16x8 bf0 = *reinterpret_cast<const bf16x8*>(bbase);
    bf16x8 bf1 = *reinterpret_cast<const bf16x8*>(bbase + 32);

    for (int bi = 0; bi < 16; ++bi) {
        bf16x8 nb0, nb1;
        if (bi < 15) {   // prefetch next b-row (overlaps MFMA + sigmoid)
            nb0 = *reinterpret_cast<const bf16x8*>(bbase + (size_t)(bi + 1) * 4096);
            nb1 = *reinterpret_cast<const bf16x8*>(bbase + (size_t)(bi + 1) * 4096 + 32);
        }
        float zo = 0.0f;
        #pragma unroll
        for (int et = 0; et < 4; ++et) {
            f32x4 acc = {cm[et][0], cm[et][1], cm[et][2], cm[et][3]};
            acc = __builtin_amdgcn_mfma_f32_16x16x32_bf16(ga[et][0], bf0, acc, 0, 0, 0);
            acc = __builtin_amdgcn_mfma_f32_16x16x32_bf16(ga[et][1], bf1, acc, 0, 0, 0);
            #pragma unroll
            for (int i = 0; i < 4; ++i)
                zo += __builtin_amdgcn_rcpf(1.0f + __expf(-acc[i])) * wv[et][i];
        }
        // sum over the 4 quads (e sub-rows); lanes differ only in quad bits
        zo += __shfl_xor(zo, 16, 64);
        zo += __shfl_xor(zo, 32, 64);
        if (quad == 0)
            zpart[((size_t)eb * 512 + b0 + bi) * 64 + o] = zo;
        bf0 = nb0; bf1 = nb1;
    }
}

// out[i] = prelu( sum_z zpart[z][i] + outB )
__global__ __launch_bounds__(256) void finish_kernel(
    const float* __restrict__ zpart, const float* __restrict__ outB,
    const float* __restrict__ preluA, float* __restrict__ out)
{
    int i = blockIdx.x * 256 + threadIdx.x;  // < 32768
    float z = 0.0f;
    for (int j = 0; j < 33; ++j) z += zpart[(size_t)j * 32768 + i];
    z += outB[0];
    float pa = preluA[0];
    out[i] = (z >= 0.0f) ? z : pa * z;
}

extern "C" void kernel_launch(void* const* d_in, const int* in_sizes, int n_in,
                              void* d_out, int out_size, void* d_ws, size_t ws_size,
                              hipStream_t stream)
{
    const float* x       = (const float*)d_in[0];
    const float* fc_in_W = (const float*)d_in[1];
    const float* fc_in_b = (const float*)d_in[2];
    const float* fc1_W   = (const float*)d_in[3];
    const float* fc1_b   = (const float*)d_in[4];
    const float* out1_W  = (const float*)d_in[5];
    const float* out1_b  = (const float*)d_in[6];
    const float* cW      = (const float*)d_in[7];
    const float* cB      = (const float*)d_in[8];
    const float* cattW   = (const float*)d_in[9];
    const float* oattW   = (const float*)d_in[10];
    const float* ntW     = (const float*)d_in[11];
    const float* tgw     = (const float*)d_in[12];
    const float* outW    = (const float*)d_in[13];
    const float* outB    = (const float*)d_in[14];
    const float* preluA  = (const float*)d_in[15];
    const float* coef_m  = (const float*)d_in[16];
    float* out = (float*)d_out;
    float* ws  = (float*)d_ws;

    // workspace layout (float offsets) — no aliasing
    unsigned short* xb      = (unsigned short*)(ws + 0);          // 524,288 f
    unsigned short* fcinWb  = (unsigned short*)(ws + 524288);     // 1,048,576 f
    unsigned short* fc1Wb   = (unsigned short*)(ws + 1572864);    // 65,536 f
    unsigned short* Wb      = (unsigned short*)(ws + 1638400);    // 2,048 f
    unsigned short* out1WbT = (unsigned short*)(ws + 1640448);    // 262,144 f
    unsigned short* Gb      = (unsigned short*)(ws + 1902592);    // 67,584 f
    float*          cfs     = ws + 1970176;                       // 131,072 f
    float*          att     = ws + 2101248;                       // 131,072 f
    unsigned short* nattb   = (unsigned short*)(ws + 2232320);    // 65,536 f
    float*          h1p     = ws + 2297856;                       // 4*524,288 f
    float*          h2p     = ws + 4395008;                       // 4*65,536 f
    unsigned short* hbT     = (unsigned short*)(ws + 4657152);    // 1,048,576 f
    float*          cpT     = ws + 5705728;                       // 8*135,168 f
    float*          cmatT   = ws + 6787072;                       // 135,168 f
    unsigned short* nt1b    = (unsigned short*)(ws + 6922240);    // 1,048,576 f
    float*          zpart   = ws + 7970816;                       // 1,081,344 f
    // total 9,052,160 floats (~36.2 MB)

    // L1: conversions (vectorized) + coef
    uber1<<<CONV_BLOCKS + 1024, 256, 0, stream>>>(
        x, fc_in_W, fc1_W, ntW, out1_W, tgw,
        xb, fcinWb, fc1Wb, Wb, out1WbT, Gb,
        coef_m, cW, cB, cattW, cfs);
    // L2: fc_in GEMM (ksplit 4) + att
    uber2<<<1024, 256, 0, stream>>>(xb, fcinWb, h1p, cfs, oattW, att);
    // L3: fc1 GEMM(fa, nparts=4) + natt
    uber3<<<192, 256, 0, stream>>>(h1p, fc_in_b, fc1Wb, h2p, ntW, att, nattb);
    // L4: out1 GEMM(fa) + cmat GEMM (ksplit 8)
    uber4<<<776, 256, 0, stream>>>(h2p, fc1_b, out1WbT, hbT, out1_b,
                                   tgw, nattb, cpT);
    // L5: nt1f + cmat reduce (nparts=8)
    uber5<<<1040, 256, 0, stream>>>(hbT, Wb, nt1b, cpT, cmatT);
    // L6: barrier-free final, L7: finish
    final_nb<<<dim3(33, 32), 256, 0, stream>>>(nt1b, Gb, cmatT, outW, zpart);
    finish_kernel<<<128, 256, 0, stream>>>(zpart, outB, preluA, out);
}